// Round 6
// baseline (940.140 us; speedup 1.0000x reference)
//
#include <hip/hip_runtime.h>
#include <hip/hip_bf16.h>
#include <stdint.h>

#define NC 8192
#define GG 512

typedef __attribute__((ext_vector_type(8))) short bf16x8;   // 8 bf16 = 4 VGPRs (MFMA A/B frag)
typedef __attribute__((ext_vector_type(4))) float fx4;      // MFMA C/D frag
typedef __attribute__((ext_vector_type(4))) unsigned int uint4v;

__device__ __forceinline__ float bf2f(short s){
  union { uint32_t u; float f; } c; c.u = ((uint32_t)(uint16_t)s) << 16; return c.f;
}
__device__ __forceinline__ short f2bf(float f){
  union { float f; uint32_t u; } c; c.f = f;
  uint32_t u = c.u;
  uint32_t r = (u + 0x7fffu + ((u >> 16) & 1u)) >> 16;   // RNE
  return (short)(uint16_t)r;
}
__device__ __forceinline__ uint32_t au(float f){
  union { float f; uint32_t u; } c; c.f = f; return c.u;
}
#if __has_builtin(__builtin_amdgcn_rcpf)
__device__ __forceinline__ float fast_rcp(float x){ return __builtin_amdgcn_rcpf(x); }
#else
__device__ __forceinline__ float fast_rcp(float x){ return 1.0f / x; }
#endif
#if __has_builtin(__builtin_amdgcn_sqrtf)
__device__ __forceinline__ float fast_sqrt(float x){ return __builtin_amdgcn_sqrtf(x); }
#else
__device__ __forceinline__ float fast_sqrt(float x){ return sqrtf(x); }
#endif
__device__ __forceinline__ float tanh_fast(float x){      // |err| ~1e-7 rel of rcp: fine at bf16
  float e = __expf(2.0f * x);
  return 1.0f - 2.0f * fast_rcp(e + 1.0f);
}
// pack two floats -> bf16 pair (round-half-up via +0x8000, then byte-perm hi16s)
__device__ __forceinline__ uint32_t pack_bf(float lo, float hi){
  return __builtin_amdgcn_perm(au(hi) + 0x8000u, au(lo) + 0x8000u, 0x07060302u);
}
__device__ __forceinline__ void g2l16(const void* g, void* l){
  __builtin_amdgcn_global_load_lds((const __attribute__((address_space(1))) void*)g,
                                   (__attribute__((address_space(3))) void*)l, 16, 0, 0);
}

// ---------------- elementwise casts ----------------
__global__ void cast_f32_bf16(const float* __restrict__ in, short* __restrict__ out, int n){
  int i = (blockIdx.x * 256 + threadIdx.x) * 4;
  if (i < n){
    float4 v = *(const float4*)(in + i);
    uint32_t lo = (uint32_t)(uint16_t)f2bf(v.x) | ((uint32_t)(uint16_t)f2bf(v.y) << 16);
    uint32_t hi = (uint32_t)(uint16_t)f2bf(v.z) | ((uint32_t)(uint16_t)f2bf(v.w) << 16);
    *(uint2*)(out + i) = make_uint2(lo, hi);
  }
}

// in f32 [R][C] -> out bf16 at out[c*ostride + roff + r']  (transpose + cast)
// permute!=0: r' permuted within each 32-group to the MFMA k-order
// (j = jt*16+q*4+r -> pos = q*8+jt*4+r) so PV B-frags come straight from QK C-frags.
__global__ void transpose_cast(const float* __restrict__ in, short* __restrict__ out,
                               int R, int C, int ostride, int roff, int permute){
  __shared__ float t[32][33];
  int c0 = blockIdx.x * 32, r0 = blockIdx.y * 32;
  int x = threadIdx.x & 31, y = threadIdx.x >> 5;  // y in 0..7
  #pragma unroll
  for (int it = 0; it < 4; ++it)
    t[y + 8*it][x] = in[(size_t)(r0 + y + 8*it) * C + c0 + x];
  __syncthreads();
  int xp = permute ? (((x >> 2) & 3) * 8 + ((x >> 4) & 1) * 4 + (x & 3)) : x;
  #pragma unroll
  for (int it = 0; it < 4; ++it)
    out[(size_t)(c0 + y + 8*it) * ostride + roff + r0 + xp] = f2bf(t[x][y + 8*it]);
}

__global__ void fill_bias(const float* __restrict__ db1, const float* __restrict__ eb1,
                          const float* __restrict__ qb1, float* __restrict__ b){
  int i = blockIdx.x * 256 + threadIdx.x;
  if (i >= 896) return;
  float v = 0.0f;
  if (i < 512) v = db1[i];
  else if (i < 768) v = eb1[i - 512];
  else if (i < 832) v = qb1[i - 768];
  b[i] = v;
}

// ---------------- GEMM: C[M][N] = A[M][K] @ B[N][K]^T ----------------
// BM=64 BN=128 BK=64, 4 waves as 2x2 of [32m x 64n], 16x16x32 bf16 MFMA.
// modes: 0 = outb = bf16(tanh(c+bias)); 1 = outf = c+bias+res; 3 = outf += scale*c
__global__ __launch_bounds__(256, 2)
void gemm_bt(const short* __restrict__ A, int lda, const short* __restrict__ B, int ldb,
             int K, int mode, const float* __restrict__ bias,
             const float* __restrict__ res, int ldres,
             float* __restrict__ outf, short* __restrict__ outb, int ldo, float scale)
{
  __shared__ __align__(16) short As[64 * 64];
  __shared__ __align__(16) short Bs[128 * 64];
  const int tid = threadIdx.x;
  const int lane = tid & 63, wave = tid >> 6;
  const int wm = wave >> 1, wn = wave & 1;
  const int l16 = lane & 15, q = lane >> 4;
  const size_t i0 = (size_t)blockIdx.y * 64;
  const int n0 = blockIdx.x * 128;
  fx4 acc[2][4] = {};

  for (int k0 = 0; k0 < K; k0 += 64){
    #pragma unroll
    for (int inst = 0; inst < 2; ++inst){              // A tile 64x64 = 8KB
      int ch = inst * 256 + tid;
      int r = ch >> 3, pc = ch & 7;
      int colc = (pc ^ (r & 7)) * 8;
      g2l16(A + (i0 + r) * (size_t)lda + k0 + colc, As + ch * 8);
    }
    #pragma unroll
    for (int inst = 0; inst < 4; ++inst){              // B tile 128x64 = 16KB
      int ch = inst * 256 + tid;
      int r = ch >> 3, pc = ch & 7;
      int colc = (pc ^ (r & 7)) * 8;
      g2l16(B + (size_t)(n0 + r) * (size_t)ldb + k0 + colc, Bs + ch * 8);
    }
    __syncthreads();
    #pragma unroll
    for (int ks = 0; ks < 2; ++ks){
      int k8 = ks * 4 + q;
      bf16x8 af[2], bfr[4];
      #pragma unroll
      for (int mi = 0; mi < 2; ++mi){
        int r = wm * 32 + mi * 16 + l16;
        af[mi] = *(const bf16x8*)(As + r * 64 + ((k8 ^ (r & 7)) << 3));
      }
      #pragma unroll
      for (int ni = 0; ni < 4; ++ni){
        int r = wn * 64 + ni * 16 + l16;
        bfr[ni] = *(const bf16x8*)(Bs + r * 64 + ((k8 ^ (r & 7)) << 3));
      }
      #pragma unroll
      for (int mi = 0; mi < 2; ++mi)
        #pragma unroll
        for (int ni = 0; ni < 4; ++ni)
          acc[mi][ni] = __builtin_amdgcn_mfma_f32_16x16x32_bf16(af[mi], bfr[ni], acc[mi][ni], 0, 0, 0);
    }
    __syncthreads();
  }
  // epilogue: C frag layout col=lane&15 (n), row=q*4+r (m)  [HW-verified R1]
  #pragma unroll
  for (int mi = 0; mi < 2; ++mi){
    #pragma unroll
    for (int ni = 0; ni < 4; ++ni){
      int n = n0 + wn * 64 + ni * 16 + l16;
      float b = bias ? bias[n] : 0.0f;
      #pragma unroll
      for (int r = 0; r < 4; ++r){
        size_t m = i0 + wm * 32 + mi * 16 + q * 4 + r;
        float v = acc[mi][ni][r];
        size_t o = m * (size_t)ldo + n;
        if (mode == 0)      outb[o] = f2bf(tanh_fast(v + b));
        else if (mode == 1) outf[o] = v + b + res[m * (size_t)ldres + n];
        else                outf[o] += v * scale;   // mode 3
      }
    }
  }
}

// ---------------- fused attention (smooth), register-resident P ----------------
// 256 threads, 4 waves = 4 distinct 16-row i-slices; each wave covers the full GT
// range. P_ij = E_j*exp(-sqrt(max(sq_i+sq_j-2*enc_i.enc_j,0)));
// OUT[i][g] = (P@V)/rowsum(P), dual f32 write. V = denoisedT (k-permuted).
// GT=128 -> 512 blocks, 32KB LDS, launch_bounds(256,4): 16 waves/CU. (R2-proven;
// R5 stagger experiment: timing-neutral, FETCH 2x -> reverted.)
template<int GT, int CH, int MODE, int ISL>
__global__ __launch_bounds__(256, (MODE == 0) ? 4 : 2)
void attn_reg(const short* __restrict__ encA, const short* __restrict__ encJ,
              const short* __restrict__ VTp,
              const float* __restrict__ sq, const float* __restrict__ E,
              float* __restrict__ out0, float* __restrict__ out1,
              short* __restrict__ outb, int ldo)
{
  constexpr int NG  = GT / 16;          // g-tiles per wave
  constexpr int KS  = CH / 32;          // MFMA k-steps per chunk
  constexpr int CPR = CH / 8;           // 16B chunks per LDS row
  constexpr int SH  = (CPR == 4) ? 1 : 0; // bank-spread shift for CH=32 rows
  constexpr int HB  = GT * CH;          // shorts per LDS buffer
  __shared__ __align__(16) short Vl[2 * HB];
  const int tid = threadIdx.x, lane = tid & 63, wave = tid >> 6;
  const int l16 = lane & 15, q = lane >> 4;
  const int ib = blockIdx.y * (64 * ISL) + wave * 16;   // slice s adds s*64
  const int g0 = blockIdx.x * GT;
  const short* Ai = encA + (size_t)blockIdx.z * NC * 32;

  bf16x8 bi[ISL];
  float sqi[ISL], lacc[ISL];
  #pragma unroll
  for (int s = 0; s < ISL; ++s){
    bi[s] = *(const bf16x8*)(Ai + (size_t)(ib + s * 64 + l16) * 32 + q * 8);
    lacc[s] = 0.f;
    sqi[s] = (MODE == 0) ? sq[ib + s * 64 + l16] : 0.f;
  }
  fx4 acc[ISL][NG] = {};
  uint4v bP[ISL][KS], bPn[ISL][KS];

  auto stage = [&](int jc, int buf){
    #pragma unroll
    for (int inst = 0; inst < HB / 2048; ++inst){
      int ch = inst * 256 + tid;
      int r = ch / CPR, pc = ch % CPR;
      int colc = (pc ^ ((r >> SH) & (CPR - 1))) * 8;
      g2l16(VTp + (size_t)(g0 + r) * NC + jc + colc, Vl + buf * HB + ch * 8);
    }
  };
  auto transform = [&](int jb, uint4v (*o)[KS]){
    #pragma unroll
    for (int ks = 0; ks < KS; ++ks){
      uint32_t dw[ISL][4];
      #pragma unroll
      for (int jt = 0; jt < 2; ++jt){
        int j0t = jb + ks * 32 + jt * 16;
        bf16x8 aj = *(const bf16x8*)(encJ + (size_t)(j0t + l16) * 32 + q * 8);
        float4 sqj = {}, Ej = {};
        if (MODE == 0){
          sqj = *(const float4*)(sq + j0t + q * 4);
          Ej  = *(const float4*)(E  + j0t + q * 4);
        }
        #pragma unroll
        for (int s = 0; s < ISL; ++s){
          fx4 c = {};
          c = __builtin_amdgcn_mfma_f32_16x16x32_bf16(aj, bi[s], c, 0, 0, 0);
          float pv[4];
          #pragma unroll
          for (int r = 0; r < 4; ++r){
            float dot = c[r];
            if (MODE == 0){
              float d2 = fmaxf(sqi[s] + ((const float*)&sqj)[r] - 2.0f * dot, 0.0f);
              float p = ((const float*)&Ej)[r] * __expf(-fast_sqrt(d2));
              lacc[s] += p;
              pv[r] = p;
            } else {
              pv[r] = fast_rcp(1.0f + __expf(-dot));
            }
          }
          dw[s][jt * 2]     = pack_bf(pv[0], pv[1]);
          dw[s][jt * 2 + 1] = pack_bf(pv[2], pv[3]);
        }
      }
      #pragma unroll
      for (int s = 0; s < ISL; ++s){
        uint4v u = { dw[s][0], dw[s][1], dw[s][2], dw[s][3] };
        o[s][ks] = u;
      }
    }
  };
  auto pv_step = [&](int buf){
    #pragma unroll
    for (int ks = 0; ks < KS; ++ks){
      int k8 = ks * 4 + q;
      #pragma unroll
      for (int gt = 0; gt < NG; ++gt){
        int rr = gt * 16 + l16;
        bf16x8 av = *(const bf16x8*)(Vl + buf * HB + rr * CH +
                                     ((k8 ^ ((rr >> SH) & (CPR - 1))) << 3));
        #pragma unroll
        for (int s = 0; s < ISL; ++s)
          acc[s][gt] = __builtin_amdgcn_mfma_f32_16x16x32_bf16(
              av, *(const bf16x8*)&bP[s][ks], acc[s][gt], 0, 0, 0);
      }
    }
  };

  stage(0, 0);
  transform(0, bP);
  __syncthreads();                       // DMA(0) drained (vmcnt before barrier)
  for (int jc = 0; jc < NC; jc += CH){
    int buf = (jc / CH) & 1;
    int nxt = jc + CH;
    if (nxt < NC){
      stage(nxt, buf ^ 1);               // DMA into other buffer (safe: barrier'd last iter)
      transform(nxt, bPn);               // VALU — interleaves with PV MFMAs below
    }
    pv_step(buf);
    #pragma unroll
    for (int s = 0; s < ISL; ++s)
      #pragma unroll
      for (int ks = 0; ks < KS; ++ks) bP[s][ks] = bPn[s][ks];
    if (nxt < NC) __syncthreads();       // PV(jc) reads done + DMA(nxt) drained
  }

  // epilogue: D frag col = i (l16), row = g (q*4+r)
  #pragma unroll
  for (int s = 0; s < ISL; ++s){
    int irow = ib + s * 64 + l16;
    if (MODE == 0){
      float v = lacc[s];                 // reduce over the 4 q-lanes of this i-row
      v += __shfl_xor(v, 16);
      v += __shfl_xor(v, 32);
      float inv = fast_rcp(v);
      #pragma unroll
      for (int gt = 0; gt < NG; ++gt){
        int g = g0 + gt * 16 + q * 4;
        float4 o;
        o.x = acc[s][gt][0] * inv; o.y = acc[s][gt][1] * inv;
        o.z = acc[s][gt][2] * inv; o.w = acc[s][gt][3] * inv;
        size_t off = (size_t)irow * GG + g;
        *(float4*)(out0 + off) = o;
        *(float4*)(out1 + off) = o;
      }
    } else {
      #pragma unroll
      for (int gt = 0; gt < NG; ++gt){
        int g = g0 + gt * 16 + q * 4;
        uint2 u;
        u.x = pack_bf(acc[s][gt][0], acc[s][gt][1]);
        u.y = pack_bf(acc[s][gt][2], acc[s][gt][3]);
        *(uint2*)(outb + (size_t)irow * ldo + (size_t)blockIdx.z * GG + g) = u;
      }
    }
  }
}

// ---------------- heads attention: WAVE-SPECIALIZED producer/consumer (R6) ----------------
// R5 falsified cross-block anti-phase (stagger took effect in j -> FETCH 2x, timing
// identical). Overlap must be engineered WITHIN a block: waves 0..7 of a 512-thread
// block round-robin over the 4 SIMDs, so SIMD s hosts wave s (producer) + wave s+4
// (consumer) -- a guaranteed VALU-wave + MFMA-wave pair per SIMD (m114: co-issue).
// Block = 64 i-rows x FULL 512 g (kills the gx=2 sigmoid duplication: 537M->268M).
// Producers (w<4): QK MFMA + sigmoid + pack for i-tile w, write ready-made B-frag
// (verbatim per-lane uint4v, same layout pv consumes) to dbuf P-LDS (2x8KB).
// Consumers (w>=4): pure PV, one g-quarter each: 64 MFMA + 24 ds_read/chunk
// (~1320cy/CU-chunk >> barrier drain -- fixes R3's CH=32 failure mode).
// All 8 waves co-stage V (CH=64, proven swizzle). LDS 128KB V + 16KB P = 144KB ->
// 1 block/CU, 2 waves/SIMD. Grid (1,128,4) = 512 blocks = 2 passes.
__global__ __launch_bounds__(512, 1)
void attn_pc(const short* __restrict__ encA, const short* __restrict__ encJ,
             const short* __restrict__ VTp, short* __restrict__ outb, int ldo)
{
  __shared__ __align__(16) short Vl[2 * 512 * 64];   // 128 KB, dbuf
  __shared__ __align__(16) short Pl[2 * 4096];       // 16 KB, dbuf (64i x 64j bf16)
  const int tid = threadIdx.x, lane = tid & 63, wave = tid >> 6;
  const int l16 = lane & 15, q = lane >> 4;
  const int i0 = blockIdx.y * 64;
  const short* Ai = encA + (size_t)blockIdx.z * NC * 32;
  const bool prod = wave < 4;
  const int cw = wave & 3;               // producer: i-tile id; consumer: g-quarter id

  bf16x8 bi = {};
  if (prod) bi = *(const bf16x8*)(Ai + (size_t)(i0 + cw * 16 + l16) * 32 + q * 8);
  fx4 acc[4][8] = {};                    // consumers: [i-tile][g-tile]

  auto stage = [&](int jc, int buf){     // all 512 threads: 64KB V chunk
    #pragma unroll
    for (int inst = 0; inst < 8; ++inst){
      int ch = inst * 512 + tid;
      int r = ch >> 3, pc = ch & 7;      // r = g-row 0..511
      int colc = (pc ^ (r & 7)) * 8;
      g2l16(VTp + (size_t)r * NC + jc + colc, Vl + buf * 32768 + ch * 8);
    }
  };
  // producer: QK for i-tile cw over 64 j; sigmoid; write B-frags to Pl[buf].
  // lane (l16,q)'s uint4v IS frag(col=i=l16, k-block=q) -- stored per-lane verbatim.
  auto transform = [&](int jb, int buf){
    #pragma unroll
    for (int ks = 0; ks < 2; ++ks){
      uint32_t dw[4];
      #pragma unroll
      for (int jt = 0; jt < 2; ++jt){
        int j0t = jb + ks * 32 + jt * 16;
        bf16x8 aj = *(const bf16x8*)(encJ + (size_t)(j0t + l16) * 32 + q * 8);
        fx4 c = {};
        c = __builtin_amdgcn_mfma_f32_16x16x32_bf16(aj, bi, c, 0, 0, 0);
        float pv[4];
        #pragma unroll
        for (int r = 0; r < 4; ++r)
          pv[r] = fast_rcp(1.0f + __expf(-c[r]));
        dw[jt * 2]     = pack_bf(pv[0], pv[1]);
        dw[jt * 2 + 1] = pack_bf(pv[2], pv[3]);
      }
      uint4v u = { dw[0], dw[1], dw[2], dw[3] };
      int fid = ((cw * 2 + ks) * 4 + q) * 16 + l16;     // [it][ks][q][l16]
      *(uint4v*)(Pl + buf * 4096 + fid * 8) = u;
    }
  };
  // consumer: PV for g-quarter cw, all 4 i-tiles. P reads: 16 lanes x consecutive
  // 16B slots = 2-way bank alias = free (m136); V reads: proven CH=64 swizzle.
  auto pv_step = [&](int buf){
    #pragma unroll
    for (int ks = 0; ks < 2; ++ks){
      int k8 = ks * 4 + q;
      bf16x8 pf[4];
      #pragma unroll
      for (int it = 0; it < 4; ++it){
        int fid = ((it * 2 + ks) * 4 + q) * 16 + l16;
        pf[it] = *(const bf16x8*)(Pl + buf * 4096 + fid * 8);
      }
      #pragma unroll
      for (int gt = 0; gt < 8; ++gt){
        int rr = cw * 128 + gt * 16 + l16;
        bf16x8 av = *(const bf16x8*)(Vl + buf * 32768 + rr * 64 + ((k8 ^ (rr & 7)) << 3));
        #pragma unroll
        for (int it = 0; it < 4; ++it)
          acc[it][gt] = __builtin_amdgcn_mfma_f32_16x16x32_bf16(av, pf[it], acc[it][gt], 0, 0, 0);
      }
    }
  };

  stage(0, 0);
  if (prod) transform(0, 0);
  __syncthreads();                       // V(0) DMA drained + P(0) written
  for (int n = 0; n < NC / 64; ++n){
    int buf = n & 1;
    int nxt = n + 1;
    if (nxt < NC / 64) stage(nxt * 64, buf ^ 1);
    if (prod){
      if (nxt < NC / 64) transform(nxt * 64, buf ^ 1);   // VALU, overlaps consumers' MFMA
    } else {
      pv_step(buf);                                      // MFMA, overlaps producers' VALU
    }
    if (nxt < NC / 64) __syncthreads();  // PV(n) reads done + V/P(nxt) ready
  }

  // epilogue (consumers): D frag col = i (l16), row = g (q*4+r)
  if (!prod){
    #pragma unroll
    for (int it = 0; it < 4; ++it){
      int irow = i0 + it * 16 + l16;
      #pragma unroll
      for (int gt = 0; gt < 8; ++gt){
        int g = cw * 128 + gt * 16 + q * 4;
        uint2 u;
        u.x = pack_bf(acc[it][gt][0], acc[it][gt][1]);
        u.y = pack_bf(acc[it][gt][2], acc[it][gt][3]);
        *(uint2*)(outb + (size_t)irow * ldo + (size_t)blockIdx.z * GG + g) = u;
      }
    }
  }
}

// ---------------- small MLP tails ----------------
// enc = Hc[:,0:256] @ eW2 + eb2 (bf16-rounded), sq = |enc|^2, Ah[h] = enc @ T[h]
__global__ void embed2_kernel(const short* __restrict__ H2, int lda,
                              const float* __restrict__ eW2,
                              const float* __restrict__ eb2, const float* __restrict__ T4,
                              short* __restrict__ encb, float* __restrict__ sq,
                              short* __restrict__ Ah)
{
  __shared__ float encS[8][32];
  int d = threadIdx.x & 31, cl = threadIdx.x >> 5;
  size_t c = (size_t)blockIdx.x * 8 + cl;
  float s = eb2[d];
  const short* hrow = H2 + c * lda;
  for (int k = 0; k < 256; ++k) s += bf2f(hrow[k]) * eW2[k * 32 + d];
  short eb = f2bf(s);
  encb[c * 32 + d] = eb;
  encS[cl][d] = bf2f(eb);
  __syncthreads();
  if (d == 0){
    float t = 0;
    for (int k = 0; k < 32; ++k) t += encS[cl][k] * encS[cl][k];
    sq[c] = t;
  }
  #pragma unroll
  for (int h = 0; h < 4; ++h){
    float a = 0;
    const float* T = T4 + h * 1024;
    for (int k = 0; k < 32; ++k) a += encS[cl][k] * T[k * 32 + d];
    Ah[(size_t)h * NC * 32 + c * 32 + d] = f2bf(a);
  }
}

// E[c] = exp(Hq[c,:64] . qW2 + qb2)   (tanh already applied by GEMM1)
__global__ void qtail_kernel(const short* __restrict__ Hq, int lda,
                             const float* __restrict__ qW2, const float* __restrict__ qb2,
                             float* __restrict__ E)
{
  int j = threadIdx.x & 63, cl = threadIdx.x >> 6;
  size_t c = (size_t)blockIdx.x * 4 + cl;
  float t = bf2f(Hq[c * lda + j]) * qW2[j];
  #pragma unroll
  for (int o = 32; o >= 1; o >>= 1) t += __shfl_xor(t, o);
  if (j == 0) E[c] = __expf(t + qb2[0]);
}

// ---------------- host ----------------
extern "C" void kernel_launch(void* const* d_in, const int* in_sizes, int n_in,
                              void* d_out, int out_size, void* d_ws, size_t ws_size,
                              hipStream_t stream)
{
  const float* raw = (const float*)d_in[0];
  const float* dW1 = (const float*)d_in[1];
  const float* db1 = (const float*)d_in[2];
  const float* dW2 = (const float*)d_in[3];
  const float* db2 = (const float*)d_in[4];
  const float* eW1 = (const float*)d_in[5];
  const float* eb1 = (const float*)d_in[6];
  const float* eW2 = (const float*)d_in[7];
  const float* eb2 = (const float*)d_in[8];
  const float* qW1 = (const float*)d_in[9];
  const float* qb1 = (const float*)d_in[10];
  const float* qW2 = (const float*)d_in[11];
  const float* qb2 = (const float*)d_in[12];
  const float* Tr  = (const float*)d_in[13];
  const float* Gr  = (const float*)d_in[14];

  float* outD = (float*)d_out;                    // denoised [8192][512]
  float* outS = outD + (size_t)NC * GG;           // smoothed
  float* outF = outS + (size_t)NC * GG;           // final

  char* ws = (char*)d_ws;
  size_t off = 0;
  auto take = [&](size_t bytes) -> char* {
    char* p = ws + off; off += (bytes + 255) & ~(size_t)255; return p;
  };
  short* Xb    = (short*)take((size_t)NC * GG * 2);       // raw bf16
  short* WcatT = (short*)take((size_t)896 * 512 * 2);     // [dW1|eW1|qW1]^T, rows 832..895 pad
  short* dW2T  = (short*)take((size_t)512 * 512 * 2);
  short* GTc   = (short*)take((size_t)512 * 2048 * 2);    // gene_responses^T concat
  float* bcat  = (float*)take((size_t)896 * 4);
  short* Hcat  = (short*)take((size_t)NC * 896 * 2);      // tanh hidden concat [cell][896]
  short* denTp = (short*)take((size_t)GG * NC * 2);       // denoised^T, k-permuted
  short* smoTp = (short*)take((size_t)GG * NC * 2);       // smoothed^T, k-permuted
  short* encb  = (short*)take((size_t)NC * 32 * 2);
  short* Ahb   = (short*)take((size_t)4 * NC * 32 * 2);
  float* sqv   = (float*)take((size_t)NC * 4);
  float* Ev    = (float*)take((size_t)NC * 4);
  short* Ucat  = (short*)take((size_t)NC * 2048 * 2);     // head outputs concat

  dim3 b256(256);
  // ---- casts / transposed weights / bias concat ----
  cast_f32_bf16<<<dim3((NC * GG) / 1024), b256, 0, stream>>>(raw, Xb, NC * GG);
  transpose_cast<<<dim3(16, 16), b256, 0, stream>>>(dW1, WcatT, 512, 512, 512, 0, 0);
  transpose_cast<<<dim3(8, 16),  b256, 0, stream>>>(eW1, WcatT + 512 * 512, 512, 256, 512, 0, 0);
  transpose_cast<<<dim3(2, 16),  b256, 0, stream>>>(qW1, WcatT + 768 * 512, 512, 64, 512, 0, 0);
  transpose_cast<<<dim3(16, 16), b256, 0, stream>>>(dW2, dW2T, 512, 512, 512, 0, 0);
  for (int h = 0; h < 4; ++h)
    transpose_cast<<<dim3(16, 16), b256, 0, stream>>>(Gr + (size_t)h * 512 * 512,
                                                      GTc, 512, 512, 2048, h * 512, 0);
  fill_bias<<<dim3(4), b256, 0, stream>>>(db1, eb1, qb1, bcat);
  // ---- fused first layer: Hcat = tanh(X @ [dW1|eW1|qW1] + bcat)  (N=896) ----
  gemm_bt<<<dim3(7, 128), b256, 0, stream>>>(Xb, 512, WcatT, 512, 512, 0, bcat,
                                             (const float*)nullptr, 0,
                                             (float*)nullptr, Hcat, 896, 1.0f);
  // ---- denoise layer 2: outD = Hcat[:,0:512] @ dW2 + db2 + raw ----
  gemm_bt<<<dim3(4, 128), b256, 0, stream>>>(Hcat, 896, dW2T, 512, 512, 1, db2,
                                             raw, 512, outD, (short*)nullptr, 512, 1.0f);
  transpose_cast<<<dim3(16, 256), b256, 0, stream>>>(outD, denTp, NC, 512, NC, 0, 1);
  // ---- embed tail + quality tail ----
  embed2_kernel<<<dim3(NC / 8), b256, 0, stream>>>(Hcat + 512, 896, eW2, eb2, Tr,
                                                   encb, sqv, Ahb);
  qtail_kernel<<<dim3(NC / 4), b256, 0, stream>>>(Hcat + 768, 896, qW2, qb2, Ev);
  // ---- fused smooth: outS = outF = softmax-weighted avg of denoised ----
  attn_reg<128, 64, 0, 1><<<dim3(4, 128, 1), b256, 0, stream>>>(
      encb, encb, denTp, sqv, Ev, outS, outF, (short*)nullptr, 0);
  transpose_cast<<<dim3(16, 256), b256, 0, stream>>>(outS, smoTp, NC, 512, NC, 0, 1);
  // ---- fused heads: Ucat[:, h*512:] = sigmoid(Ah_h enc^T) @ smoothed ----
  // wave-specialized producer/consumer: VALU (sigmoid) and MFMA (PV) on separate
  // waves, one pair per SIMD; sigmoid computed once per (i,j,h)
  attn_pc<<<dim3(1, NC / 64, 4), dim3(512), 0, stream>>>(Ahb, encb, smoTp, Ucat, 2048);
  // ---- final += (Ucat @ GTcat^T) / N   (single K=2048 GEMM) ----
  gemm_bt<<<dim3(4, 128), b256, 0, stream>>>(Ucat, 2048, GTc, 2048, 2048,
                                             3, (const float*)nullptr,
                                             (const float*)nullptr, 0,
                                             outF, (short*)nullptr, 512, 1.0f / NC);
}

// Round 7
// 750.001 us; speedup vs baseline: 1.2535x; 1.2535x over previous
//
#include <hip/hip_runtime.h>
#include <hip/hip_bf16.h>
#include <stdint.h>
#if !__has_builtin(__builtin_amdgcn_cvt_pk_fp8_f32)
#include <hip/hip_fp8.h>
#endif

#define NC 8192
#define GG 512

typedef __attribute__((ext_vector_type(8))) short bf16x8;   // 8 bf16 = 4 VGPRs (MFMA A/B frag)
typedef __attribute__((ext_vector_type(4))) float fx4;      // MFMA C/D frag
typedef __attribute__((ext_vector_type(4))) unsigned int uint4v;
typedef __attribute__((ext_vector_type(2))) long long llx2; // 16B = two fp8 A-frags

__device__ __forceinline__ float bf2f(short s){
  union { uint32_t u; float f; } c; c.u = ((uint32_t)(uint16_t)s) << 16; return c.f;
}
__device__ __forceinline__ short f2bf(float f){
  union { float f; uint32_t u; } c; c.f = f;
  uint32_t u = c.u;
  uint32_t r = (u + 0x7fffu + ((u >> 16) & 1u)) >> 16;   // RNE
  return (short)(uint16_t)r;
}
__device__ __forceinline__ uint32_t au(float f){
  union { float f; uint32_t u; } c; c.f = f; return c.u;
}
#if __has_builtin(__builtin_amdgcn_rcpf)
__device__ __forceinline__ float fast_rcp(float x){ return __builtin_amdgcn_rcpf(x); }
#else
__device__ __forceinline__ float fast_rcp(float x){ return 1.0f / x; }
#endif
#if __has_builtin(__builtin_amdgcn_sqrtf)
__device__ __forceinline__ float fast_sqrt(float x){ return __builtin_amdgcn_sqrtf(x); }
#else
__device__ __forceinline__ float fast_sqrt(float x){ return sqrtf(x); }
#endif
__device__ __forceinline__ float tanh_fast(float x){      // |err| ~1e-7 rel of rcp: fine at bf16
  float e = __expf(2.0f * x);
  return 1.0f - 2.0f * fast_rcp(e + 1.0f);
}
// pack two floats -> bf16 pair (round-half-up via +0x8000, then byte-perm hi16s)
__device__ __forceinline__ uint32_t pack_bf(float lo, float hi){
  return __builtin_amdgcn_perm(au(hi) + 0x8000u, au(lo) + 0x8000u, 0x07060302u);
}
// pack two floats -> 2 x fp8 e4m3 (OCP on gfx950) into lo/hi half of a dword
template<bool HI>
__device__ __forceinline__ uint32_t pk_fp8(float a, float b, uint32_t old){
#if __has_builtin(__builtin_amdgcn_cvt_pk_fp8_f32)
  return (uint32_t)__builtin_amdgcn_cvt_pk_fp8_f32(a, b, (int)old, HI);
#else
  __hip_fp8_e4m3 fa(a), fb(b);
  uint32_t v = (uint32_t)fa.__x | ((uint32_t)fb.__x << 8);
  return HI ? ((old & 0x0000ffffu) | (v << 16)) : ((old & 0xffff0000u) | v);
#endif
}
__device__ __forceinline__ void g2l16(const void* g, void* l){
  __builtin_amdgcn_global_load_lds((const __attribute__((address_space(1))) void*)g,
                                   (__attribute__((address_space(3))) void*)l, 16, 0, 0);
}

// ---------------- elementwise casts ----------------
__global__ void cast_f32_bf16(const float* __restrict__ in, short* __restrict__ out, int n){
  int i = (blockIdx.x * 256 + threadIdx.x) * 4;
  if (i < n){
    float4 v = *(const float4*)(in + i);
    uint32_t lo = (uint32_t)(uint16_t)f2bf(v.x) | ((uint32_t)(uint16_t)f2bf(v.y) << 16);
    uint32_t hi = (uint32_t)(uint16_t)f2bf(v.z) | ((uint32_t)(uint16_t)f2bf(v.w) << 16);
    *(uint2*)(out + i) = make_uint2(lo, hi);
  }
}

// in f32 [R][C] -> out bf16 at out[c*ostride + roff + r']  (transpose + cast)
// permute!=0: r' permuted within each 32-group to the MFMA k-order
// (j = jt*16+q*4+r -> pos = q*8+jt*4+r) so PV B-frags come straight from QK C-frags.
__global__ void transpose_cast(const float* __restrict__ in, short* __restrict__ out,
                               int R, int C, int ostride, int roff, int permute){
  __shared__ float t[32][33];
  int c0 = blockIdx.x * 32, r0 = blockIdx.y * 32;
  int x = threadIdx.x & 31, y = threadIdx.x >> 5;  // y in 0..7
  #pragma unroll
  for (int it = 0; it < 4; ++it)
    t[y + 8*it][x] = in[(size_t)(r0 + y + 8*it) * C + c0 + x];
  __syncthreads();
  int xp = permute ? (((x >> 2) & 3) * 8 + ((x >> 4) & 1) * 4 + (x & 3)) : x;
  #pragma unroll
  for (int it = 0; it < 4; ++it)
    out[(size_t)(c0 + y + 8*it) * ostride + roff + r0 + xp] = f2bf(t[x][y + 8*it]);
}

// f32 [R][512] -> fp8 e4m3 transposed [512][NC] with the fp8 PV k-order:
// within each 64-j chunk, octet o = q*2 + ks (ks = 32-group), pos = o*8 + jt*4 + r.
// One ds_read_b128 then yields the A-frags for BOTH ks MFMAs of a lane.
__global__ void transpose_cast8(const float* __restrict__ in, unsigned char* __restrict__ out,
                                int C, int ostride){
  __shared__ float t[32][33];
  int c0 = blockIdx.x * 32, r0 = blockIdx.y * 32;
  int x = threadIdx.x & 31, y = threadIdx.x >> 5;
  #pragma unroll
  for (int it = 0; it < 4; ++it)
    t[y + 8*it][x] = in[(size_t)(r0 + y + 8*it) * C + c0 + x];
  __syncthreads();
  int xp = ((x >> 2) & 3) * 16 + ((r0 >> 5) & 1) * 8 + ((x >> 4) & 1) * 4 + (x & 3);
  int cb = r0 & ~63;
  #pragma unroll
  for (int it = 0; it < 4; ++it){
    float v = t[x][y + 8*it];
    out[(size_t)(c0 + y + 8*it) * ostride + cb + xp] =
        (unsigned char)(pk_fp8<false>(v, v, 0u) & 0xffu);
  }
}

__global__ void fill_bias(const float* __restrict__ db1, const float* __restrict__ eb1,
                          const float* __restrict__ qb1, float* __restrict__ b){
  int i = blockIdx.x * 256 + threadIdx.x;
  if (i >= 896) return;
  float v = 0.0f;
  if (i < 512) v = db1[i];
  else if (i < 768) v = eb1[i - 512];
  else if (i < 832) v = qb1[i - 768];
  b[i] = v;
}

// ---------------- GEMM: C[M][N] = A[M][K] @ B[N][K]^T ----------------
// BM=64 BN=128 BK=64, 4 waves as 2x2 of [32m x 64n], 16x16x32 bf16 MFMA.
// modes: 0 = outb = bf16(tanh(c+bias)); 1 = outf = c+bias+res; 3 = outf += scale*c
__global__ __launch_bounds__(256, 2)
void gemm_bt(const short* __restrict__ A, int lda, const short* __restrict__ B, int ldb,
             int K, int mode, const float* __restrict__ bias,
             const float* __restrict__ res, int ldres,
             float* __restrict__ outf, short* __restrict__ outb, int ldo, float scale)
{
  __shared__ __align__(16) short As[64 * 64];
  __shared__ __align__(16) short Bs[128 * 64];
  const int tid = threadIdx.x;
  const int lane = tid & 63, wave = tid >> 6;
  const int wm = wave >> 1, wn = wave & 1;
  const int l16 = lane & 15, q = lane >> 4;
  const size_t i0 = (size_t)blockIdx.y * 64;
  const int n0 = blockIdx.x * 128;
  fx4 acc[2][4] = {};

  for (int k0 = 0; k0 < K; k0 += 64){
    #pragma unroll
    for (int inst = 0; inst < 2; ++inst){              // A tile 64x64 = 8KB
      int ch = inst * 256 + tid;
      int r = ch >> 3, pc = ch & 7;
      int colc = (pc ^ (r & 7)) * 8;
      g2l16(A + (i0 + r) * (size_t)lda + k0 + colc, As + ch * 8);
    }
    #pragma unroll
    for (int inst = 0; inst < 4; ++inst){              // B tile 128x64 = 16KB
      int ch = inst * 256 + tid;
      int r = ch >> 3, pc = ch & 7;
      int colc = (pc ^ (r & 7)) * 8;
      g2l16(B + (size_t)(n0 + r) * (size_t)ldb + k0 + colc, Bs + ch * 8);
    }
    __syncthreads();
    #pragma unroll
    for (int ks = 0; ks < 2; ++ks){
      int k8 = ks * 4 + q;
      bf16x8 af[2], bfr[4];
      #pragma unroll
      for (int mi = 0; mi < 2; ++mi){
        int r = wm * 32 + mi * 16 + l16;
        af[mi] = *(const bf16x8*)(As + r * 64 + ((k8 ^ (r & 7)) << 3));
      }
      #pragma unroll
      for (int ni = 0; ni < 4; ++ni){
        int r = wn * 64 + ni * 16 + l16;
        bfr[ni] = *(const bf16x8*)(Bs + r * 64 + ((k8 ^ (r & 7)) << 3));
      }
      #pragma unroll
      for (int mi = 0; mi < 2; ++mi)
        #pragma unroll
        for (int ni = 0; ni < 4; ++ni)
          acc[mi][ni] = __builtin_amdgcn_mfma_f32_16x16x32_bf16(af[mi], bfr[ni], acc[mi][ni], 0, 0, 0);
    }
    __syncthreads();
  }
  // epilogue: C frag layout col=lane&15 (n), row=q*4+r (m)  [HW-verified R1]
  #pragma unroll
  for (int mi = 0; mi < 2; ++mi){
    #pragma unroll
    for (int ni = 0; ni < 4; ++ni){
      int n = n0 + wn * 64 + ni * 16 + l16;
      float b = bias ? bias[n] : 0.0f;
      #pragma unroll
      for (int r = 0; r < 4; ++r){
        size_t m = i0 + wm * 32 + mi * 16 + q * 4 + r;
        float v = acc[mi][ni][r];
        size_t o = m * (size_t)ldo + n;
        if (mode == 0)      outb[o] = f2bf(tanh_fast(v + b));
        else if (mode == 1) outf[o] = v + b + res[m * (size_t)ldres + n];
        else                outf[o] += v * scale;   // mode 3
      }
    }
  }
}

// ---------------- fused attention (smooth), register-resident P ----------------
// 256 threads, 4 waves = 4 distinct 16-row i-slices; each wave covers the full GT
// range. P_ij = E_j*exp(-sqrt(max(sq_i+sq_j-2*enc_i.enc_j,0)));
// OUT[i][g] = (P@V)/rowsum(P), dual f32 write. V = denoisedT (k-permuted).
// GT=128 -> 512 blocks, 32KB LDS, launch_bounds(256,4): 16 waves/CU. (R2-proven.)
template<int GT, int CH, int MODE, int ISL>
__global__ __launch_bounds__(256, (MODE == 0) ? 4 : 2)
void attn_reg(const short* __restrict__ encA, const short* __restrict__ encJ,
              const short* __restrict__ VTp,
              const float* __restrict__ sq, const float* __restrict__ E,
              float* __restrict__ out0, float* __restrict__ out1,
              short* __restrict__ outb, int ldo)
{
  constexpr int NG  = GT / 16;          // g-tiles per wave
  constexpr int KS  = CH / 32;          // MFMA k-steps per chunk
  constexpr int CPR = CH / 8;           // 16B chunks per LDS row
  constexpr int SH  = (CPR == 4) ? 1 : 0; // bank-spread shift for CH=32 rows
  constexpr int HB  = GT * CH;          // shorts per LDS buffer
  __shared__ __align__(16) short Vl[2 * HB];
  const int tid = threadIdx.x, lane = tid & 63, wave = tid >> 6;
  const int l16 = lane & 15, q = lane >> 4;
  const int ib = blockIdx.y * (64 * ISL) + wave * 16;   // slice s adds s*64
  const int g0 = blockIdx.x * GT;
  const short* Ai = encA + (size_t)blockIdx.z * NC * 32;

  bf16x8 bi[ISL];
  float sqi[ISL], lacc[ISL];
  #pragma unroll
  for (int s = 0; s < ISL; ++s){
    bi[s] = *(const bf16x8*)(Ai + (size_t)(ib + s * 64 + l16) * 32 + q * 8);
    lacc[s] = 0.f;
    sqi[s] = (MODE == 0) ? sq[ib + s * 64 + l16] : 0.f;
  }
  fx4 acc[ISL][NG] = {};
  uint4v bP[ISL][KS], bPn[ISL][KS];

  auto stage = [&](int jc, int buf){
    #pragma unroll
    for (int inst = 0; inst < HB / 2048; ++inst){
      int ch = inst * 256 + tid;
      int r = ch / CPR, pc = ch % CPR;
      int colc = (pc ^ ((r >> SH) & (CPR - 1))) * 8;
      g2l16(VTp + (size_t)(g0 + r) * NC + jc + colc, Vl + buf * HB + ch * 8);
    }
  };
  auto transform = [&](int jb, uint4v (*o)[KS]){
    #pragma unroll
    for (int ks = 0; ks < KS; ++ks){
      uint32_t dw[ISL][4];
      #pragma unroll
      for (int jt = 0; jt < 2; ++jt){
        int j0t = jb + ks * 32 + jt * 16;
        bf16x8 aj = *(const bf16x8*)(encJ + (size_t)(j0t + l16) * 32 + q * 8);
        float4 sqj = {}, Ej = {};
        if (MODE == 0){
          sqj = *(const float4*)(sq + j0t + q * 4);
          Ej  = *(const float4*)(E  + j0t + q * 4);
        }
        #pragma unroll
        for (int s = 0; s < ISL; ++s){
          fx4 c = {};
          c = __builtin_amdgcn_mfma_f32_16x16x32_bf16(aj, bi[s], c, 0, 0, 0);
          float pv[4];
          #pragma unroll
          for (int r = 0; r < 4; ++r){
            float dot = c[r];
            if (MODE == 0){
              float d2 = fmaxf(sqi[s] + ((const float*)&sqj)[r] - 2.0f * dot, 0.0f);
              float p = ((const float*)&Ej)[r] * __expf(-fast_sqrt(d2));
              lacc[s] += p;
              pv[r] = p;
            } else {
              pv[r] = fast_rcp(1.0f + __expf(-dot));
            }
          }
          dw[s][jt * 2]     = pack_bf(pv[0], pv[1]);
          dw[s][jt * 2 + 1] = pack_bf(pv[2], pv[3]);
        }
      }
      #pragma unroll
      for (int s = 0; s < ISL; ++s){
        uint4v u = { dw[s][0], dw[s][1], dw[s][2], dw[s][3] };
        o[s][ks] = u;
      }
    }
  };
  auto pv_step = [&](int buf){
    #pragma unroll
    for (int ks = 0; ks < KS; ++ks){
      int k8 = ks * 4 + q;
      #pragma unroll
      for (int gt = 0; gt < NG; ++gt){
        int rr = gt * 16 + l16;
        bf16x8 av = *(const bf16x8*)(Vl + buf * HB + rr * CH +
                                     ((k8 ^ ((rr >> SH) & (CPR - 1))) << 3));
        #pragma unroll
        for (int s = 0; s < ISL; ++s)
          acc[s][gt] = __builtin_amdgcn_mfma_f32_16x16x32_bf16(
              av, *(const bf16x8*)&bP[s][ks], acc[s][gt], 0, 0, 0);
      }
    }
  };

  stage(0, 0);
  transform(0, bP);
  __syncthreads();                       // DMA(0) drained (vmcnt before barrier)
  for (int jc = 0; jc < NC; jc += CH){
    int buf = (jc / CH) & 1;
    int nxt = jc + CH;
    if (nxt < NC){
      stage(nxt, buf ^ 1);               // DMA into other buffer (safe: barrier'd last iter)
      transform(nxt, bPn);               // VALU — interleaves with PV MFMAs below
    }
    pv_step(buf);
    #pragma unroll
    for (int s = 0; s < ISL; ++s)
      #pragma unroll
      for (int ks = 0; ks < KS; ++ks) bP[s][ks] = bPn[s][ks];
    if (nxt < NC) __syncthreads();       // PV(jc) reads done + DMA(nxt) drained
  }

  // epilogue: D frag col = i (l16), row = g (q*4+r)
  #pragma unroll
  for (int s = 0; s < ISL; ++s){
    int irow = ib + s * 64 + l16;
    if (MODE == 0){
      float v = lacc[s];                 // reduce over the 4 q-lanes of this i-row
      v += __shfl_xor(v, 16);
      v += __shfl_xor(v, 32);
      float inv = fast_rcp(v);
      #pragma unroll
      for (int gt = 0; gt < NG; ++gt){
        int g = g0 + gt * 16 + q * 4;
        float4 o;
        o.x = acc[s][gt][0] * inv; o.y = acc[s][gt][1] * inv;
        o.z = acc[s][gt][2] * inv; o.w = acc[s][gt][3] * inv;
        size_t off = (size_t)irow * GG + g;
        *(float4*)(out0 + off) = o;
        *(float4*)(out1 + off) = o;
      }
    } else {
      #pragma unroll
      for (int gt = 0; gt < NG; ++gt){
        int g = g0 + gt * 16 + q * 4;
        uint2 u;
        u.x = pack_bf(acc[s][gt][0], acc[s][gt][1]);
        u.y = pack_bf(acc[s][gt][2], acc[s][gt][3]);
        *(uint2*)(outb + (size_t)irow * ldo + (size_t)blockIdx.z * GG + g) = u;
      }
    }
  }
}

// ---------------- heads attention, fp8 PV, dup=1 (R7) ----------------
// Keeps the R2 schedule verbatim (2 blk/CU, CH=64, DMA-ahead, 1 barrier/chunk —
// the only structure that survived R3/R4/R6). fp8 V (e4m3) shrinks the V buffer
// to 512x64x1B = 32KB/buf -> full g=512 per block fits at 2 blk/CU -> NO g-split:
// sigmoid count 537M -> 268M (the dominant VALU term halves). P also fp8 (B-op).
// Error enters only inter=(CI@smo)@G/N: RMS ~5e-3 absolute on final, inside budget.
// V layout: 64B rows, 16B slot s at (s ^ ((r>>1)&3)) [R1-verified involution];
// within a slot-pair read (b128), octet o = q*2+ks (baked by transpose_cast8) so
// one ds_read_b128 feeds both ks MFMAs. Per chunk/wave: 4 QK + 64 PV MFMA,
// 32 ds_read_b128, 16 sigmoids/lane, 8 DMA. acc 128 VGPR -> launch_bounds(256,2).
__global__ __launch_bounds__(256, 2)
void attn_f8(const short* __restrict__ encA, const short* __restrict__ encJ,
             const unsigned char* __restrict__ V8, short* __restrict__ outb, int ldo)
{
  __shared__ __align__(16) unsigned char Vl[2 * 512 * 64];   // 64 KB dbuf
  const int tid = threadIdx.x, lane = tid & 63, wave = tid >> 6;
  const int l16 = lane & 15, q = lane >> 4;
  const int i0 = blockIdx.y * 64 + wave * 16;
  const short* Ai = encA + (size_t)blockIdx.z * NC * 32;
  const bf16x8 bi = *(const bf16x8*)(Ai + (size_t)(i0 + l16) * 32 + q * 8);
  fx4 acc[32] = {};
  uint2 bP[2], bPn[2];

  auto stage = [&](int jc, int buf){
    #pragma unroll
    for (int inst = 0; inst < 8; ++inst){
      int ch = inst * 256 + tid;          // 16B units, 0..2047
      int r = ch >> 2, pc = ch & 3;       // r = g-row 0..511
      int colc = (pc ^ ((r >> 1) & 3)) * 16;
      g2l16(V8 + (size_t)r * NC + jc + colc, Vl + buf * 32768 + ch * 16);
    }
  };
  // QK (bf16) + sigmoid -> fp8 B-frag: i64 byte t = k-pos q*8+t; value order
  // [jt0: r0..3][jt1: r0..3] matches the V permute (pos = o*8 + jt*4 + r).
  auto transform = [&](int jb, uint2* o){
    #pragma unroll
    for (int ks = 0; ks < 2; ++ks){
      uint32_t dw[2];
      #pragma unroll
      for (int jt = 0; jt < 2; ++jt){
        int j0t = jb + ks * 32 + jt * 16;
        bf16x8 aj = *(const bf16x8*)(encJ + (size_t)(j0t + l16) * 32 + q * 8);
        fx4 c = {};
        c = __builtin_amdgcn_mfma_f32_16x16x32_bf16(aj, bi, c, 0, 0, 0);
        float p[4];
        #pragma unroll
        for (int r = 0; r < 4; ++r)
          p[r] = fast_rcp(1.0f + __expf(-c[r]));
        dw[jt] = pk_fp8<true>(p[2], p[3], pk_fp8<false>(p[0], p[1], 0u));
      }
      o[ks] = make_uint2(dw[0], dw[1]);
    }
  };
  auto pv_step = [&](int buf){
    const long long bp0 = *(const long long*)&bP[0];
    const long long bp1 = *(const long long*)&bP[1];
    #pragma unroll
    for (int gt = 0; gt < 32; ++gt){
      int rr = gt * 16 + l16;
      llx2 av = *(const llx2*)(Vl + buf * 32768 + rr * 64 + ((q ^ ((rr >> 1) & 3)) << 4));
      acc[gt] = __builtin_amdgcn_mfma_f32_16x16x32_fp8_fp8(av[0], bp0, acc[gt], 0, 0, 0);
      acc[gt] = __builtin_amdgcn_mfma_f32_16x16x32_fp8_fp8(av[1], bp1, acc[gt], 0, 0, 0);
    }
  };

  stage(0, 0);
  transform(0, bP);
  __syncthreads();                       // DMA(0) drained
  for (int jc = 0; jc < NC; jc += 64){
    int buf = (jc >> 6) & 1;
    int nxt = jc + 64;
    if (nxt < NC){
      stage(nxt, buf ^ 1);
      transform(nxt, bPn);
    }
    pv_step(buf);
    bP[0] = bPn[0]; bP[1] = bPn[1];
    if (nxt < NC) __syncthreads();
  }

  // epilogue: D frag col = i (l16), row = g (q*4+r)
  #pragma unroll
  for (int gt = 0; gt < 32; ++gt){
    int g = gt * 16 + q * 4;
    uint2 u;
    u.x = pack_bf(acc[gt][0], acc[gt][1]);
    u.y = pack_bf(acc[gt][2], acc[gt][3]);
    *(uint2*)(outb + (size_t)(i0 + l16) * ldo + (size_t)blockIdx.z * GG + g) = u;
  }
}

// ---------------- small MLP tails ----------------
// enc = Hc[:,0:256] @ eW2 + eb2 (bf16-rounded), sq = |enc|^2, Ah[h] = enc @ T[h]
__global__ void embed2_kernel(const short* __restrict__ H2, int lda,
                              const float* __restrict__ eW2,
                              const float* __restrict__ eb2, const float* __restrict__ T4,
                              short* __restrict__ encb, float* __restrict__ sq,
                              short* __restrict__ Ah)
{
  __shared__ float encS[8][32];
  int d = threadIdx.x & 31, cl = threadIdx.x >> 5;
  size_t c = (size_t)blockIdx.x * 8 + cl;
  float s = eb2[d];
  const short* hrow = H2 + c * lda;
  for (int k = 0; k < 256; ++k) s += bf2f(hrow[k]) * eW2[k * 32 + d];
  short eb = f2bf(s);
  encb[c * 32 + d] = eb;
  encS[cl][d] = bf2f(eb);
  __syncthreads();
  if (d == 0){
    float t = 0;
    for (int k = 0; k < 32; ++k) t += encS[cl][k] * encS[cl][k];
    sq[c] = t;
  }
  #pragma unroll
  for (int h = 0; h < 4; ++h){
    float a = 0;
    const float* T = T4 + h * 1024;
    for (int k = 0; k < 32; ++k) a += encS[cl][k] * T[k * 32 + d];
    Ah[(size_t)h * NC * 32 + c * 32 + d] = f2bf(a);
  }
}

// E[c] = exp(Hq[c,:64] . qW2 + qb2)   (tanh already applied by GEMM1)
__global__ void qtail_kernel(const short* __restrict__ Hq, int lda,
                             const float* __restrict__ qW2, const float* __restrict__ qb2,
                             float* __restrict__ E)
{
  int j = threadIdx.x & 63, cl = threadIdx.x >> 6;
  size_t c = (size_t)blockIdx.x * 4 + cl;
  float t = bf2f(Hq[c * lda + j]) * qW2[j];
  #pragma unroll
  for (int o = 32; o >= 1; o >>= 1) t += __shfl_xor(t, o);
  if (j == 0) E[c] = __expf(t + qb2[0]);
}

// ---------------- host ----------------
extern "C" void kernel_launch(void* const* d_in, const int* in_sizes, int n_in,
                              void* d_out, int out_size, void* d_ws, size_t ws_size,
                              hipStream_t stream)
{
  const float* raw = (const float*)d_in[0];
  const float* dW1 = (const float*)d_in[1];
  const float* db1 = (const float*)d_in[2];
  const float* dW2 = (const float*)d_in[3];
  const float* db2 = (const float*)d_in[4];
  const float* eW1 = (const float*)d_in[5];
  const float* eb1 = (const float*)d_in[6];
  const float* eW2 = (const float*)d_in[7];
  const float* eb2 = (const float*)d_in[8];
  const float* qW1 = (const float*)d_in[9];
  const float* qb1 = (const float*)d_in[10];
  const float* qW2 = (const float*)d_in[11];
  const float* qb2 = (const float*)d_in[12];
  const float* Tr  = (const float*)d_in[13];
  const float* Gr  = (const float*)d_in[14];

  float* outD = (float*)d_out;                    // denoised [8192][512]
  float* outS = outD + (size_t)NC * GG;           // smoothed
  float* outF = outS + (size_t)NC * GG;           // final

  char* ws = (char*)d_ws;
  size_t off = 0;
  auto take = [&](size_t bytes) -> char* {
    char* p = ws + off; off += (bytes + 255) & ~(size_t)255; return p;
  };
  short* Xb    = (short*)take((size_t)NC * GG * 2);       // raw bf16
  short* WcatT = (short*)take((size_t)896 * 512 * 2);     // [dW1|eW1|qW1]^T, rows 832..895 pad
  short* dW2T  = (short*)take((size_t)512 * 512 * 2);
  short* GTc   = (short*)take((size_t)512 * 2048 * 2);    // gene_responses^T concat
  float* bcat  = (float*)take((size_t)896 * 4);
  short* Hcat  = (short*)take((size_t)NC * 896 * 2);      // tanh hidden concat [cell][896]
  short* denTp = (short*)take((size_t)GG * NC * 2);       // denoised^T, k-permuted
  unsigned char* smoT8 = (unsigned char*)take((size_t)GG * NC);  // smoothed^T fp8, k-permuted
  short* encb  = (short*)take((size_t)NC * 32 * 2);
  short* Ahb   = (short*)take((size_t)4 * NC * 32 * 2);
  float* sqv   = (float*)take((size_t)NC * 4);
  float* Ev    = (float*)take((size_t)NC * 4);
  short* Ucat  = (short*)take((size_t)NC * 2048 * 2);     // head outputs concat

  dim3 b256(256);
  // ---- casts / transposed weights / bias concat ----
  cast_f32_bf16<<<dim3((NC * GG) / 1024), b256, 0, stream>>>(raw, Xb, NC * GG);
  transpose_cast<<<dim3(16, 16), b256, 0, stream>>>(dW1, WcatT, 512, 512, 512, 0, 0);
  transpose_cast<<<dim3(8, 16),  b256, 0, stream>>>(eW1, WcatT + 512 * 512, 512, 256, 512, 0, 0);
  transpose_cast<<<dim3(2, 16),  b256, 0, stream>>>(qW1, WcatT + 768 * 512, 512, 64, 512, 0, 0);
  transpose_cast<<<dim3(16, 16), b256, 0, stream>>>(dW2, dW2T, 512, 512, 512, 0, 0);
  for (int h = 0; h < 4; ++h)
    transpose_cast<<<dim3(16, 16), b256, 0, stream>>>(Gr + (size_t)h * 512 * 512,
                                                      GTc, 512, 512, 2048, h * 512, 0);
  fill_bias<<<dim3(4), b256, 0, stream>>>(db1, eb1, qb1, bcat);
  // ---- fused first layer: Hcat = tanh(X @ [dW1|eW1|qW1] + bcat)  (N=896) ----
  gemm_bt<<<dim3(7, 128), b256, 0, stream>>>(Xb, 512, WcatT, 512, 512, 0, bcat,
                                             (const float*)nullptr, 0,
                                             (float*)nullptr, Hcat, 896, 1.0f);
  // ---- denoise layer 2: outD = Hcat[:,0:512] @ dW2 + db2 + raw ----
  gemm_bt<<<dim3(4, 128), b256, 0, stream>>>(Hcat, 896, dW2T, 512, 512, 1, db2,
                                             raw, 512, outD, (short*)nullptr, 512, 1.0f);
  transpose_cast<<<dim3(16, 256), b256, 0, stream>>>(outD, denTp, NC, 512, NC, 0, 1);
  // ---- embed tail + quality tail ----
  embed2_kernel<<<dim3(NC / 8), b256, 0, stream>>>(Hcat + 512, 896, eW2, eb2, Tr,
                                                   encb, sqv, Ahb);
  qtail_kernel<<<dim3(NC / 4), b256, 0, stream>>>(Hcat + 768, 896, qW2, qb2, Ev);
  // ---- fused smooth: outS = outF = softmax-weighted avg of denoised ----
  attn_reg<128, 64, 0, 1><<<dim3(4, 128, 1), b256, 0, stream>>>(
      encb, encb, denTp, sqv, Ev, outS, outF, (short*)nullptr, 0);
  transpose_cast8<<<dim3(16, 256), b256, 0, stream>>>(outS, smoT8, 512, NC);
  // ---- fused heads: Ucat[:, h*512:] = sigmoid(Ah_h enc^T) @ smoothed ----
  // fp8 V/P, full-g blocks (dup=1): half the sigmoids, R2-proven schedule
  attn_f8<<<dim3(1, 128, 4), b256, 0, stream>>>(Ahb, encb, smoT8, Ucat, 2048);
  // ---- final += (Ucat @ GTcat^T) / N   (single K=2048 GEMM) ----
  gemm_bt<<<dim3(4, 128), b256, 0, stream>>>(Ucat, 2048, GTc, 2048, 2048,
                                             3, (const float*)nullptr,
                                             (const float*)nullptr, 0,
                                             outF, (short*)nullptr, 512, 1.0f / NC);
}

// Round 8
// 720.774 us; speedup vs baseline: 1.3043x; 1.0405x over previous
//
#include <hip/hip_runtime.h>
#include <hip/hip_bf16.h>
#include <stdint.h>
#if !__has_builtin(__builtin_amdgcn_cvt_pk_fp8_f32)
#include <hip/hip_fp8.h>
#endif

#define NC 8192
#define GG 512

typedef __attribute__((ext_vector_type(8))) short bf16x8;   // 8 bf16 = 4 VGPRs (MFMA A/B frag)
typedef __attribute__((ext_vector_type(4))) float fx4;      // MFMA C/D frag
typedef __attribute__((ext_vector_type(4))) unsigned int uint4v;
typedef __attribute__((ext_vector_type(2))) long long llx2; // 16B = two fp8 A/B-frags

__device__ __forceinline__ float bf2f(short s){
  union { uint32_t u; float f; } c; c.u = ((uint32_t)(uint16_t)s) << 16; return c.f;
}
__device__ __forceinline__ short f2bf(float f){
  union { float f; uint32_t u; } c; c.f = f;
  uint32_t u = c.u;
  uint32_t r = (u + 0x7fffu + ((u >> 16) & 1u)) >> 16;   // RNE
  return (short)(uint16_t)r;
}
__device__ __forceinline__ uint32_t au(float f){
  union { float f; uint32_t u; } c; c.f = f; return c.u;
}
#if __has_builtin(__builtin_amdgcn_rcpf)
__device__ __forceinline__ float fast_rcp(float x){ return __builtin_amdgcn_rcpf(x); }
#else
__device__ __forceinline__ float fast_rcp(float x){ return 1.0f / x; }
#endif
#if __has_builtin(__builtin_amdgcn_sqrtf)
__device__ __forceinline__ float fast_sqrt(float x){ return __builtin_amdgcn_sqrtf(x); }
#else
__device__ __forceinline__ float fast_sqrt(float x){ return sqrtf(x); }
#endif
__device__ __forceinline__ float tanh_fast(float x){      // |err| ~1e-7 rel of rcp: fine at bf16
  float e = __expf(2.0f * x);
  return 1.0f - 2.0f * fast_rcp(e + 1.0f);
}
// pack two floats -> bf16 pair (round-half-up via +0x8000, then byte-perm hi16s)
__device__ __forceinline__ uint32_t pack_bf(float lo, float hi){
  return __builtin_amdgcn_perm(au(hi) + 0x8000u, au(lo) + 0x8000u, 0x07060302u);
}
// pack two floats -> 2 x fp8 e4m3 (OCP on gfx950) into lo/hi half of a dword
template<bool HI>
__device__ __forceinline__ uint32_t pk_fp8(float a, float b, uint32_t old){
#if __has_builtin(__builtin_amdgcn_cvt_pk_fp8_f32)
  return (uint32_t)__builtin_amdgcn_cvt_pk_fp8_f32(a, b, (int)old, HI);
#else
  __hip_fp8_e4m3 fa(a), fb(b);
  uint32_t v = (uint32_t)fa.__x | ((uint32_t)fb.__x << 8);
  return HI ? ((old & 0x0000ffffu) | (v << 16)) : ((old & 0xffff0000u) | v);
#endif
}
__device__ __forceinline__ void g2l16(const void* g, void* l){
  __builtin_amdgcn_global_load_lds((const __attribute__((address_space(1))) void*)g,
                                   (__attribute__((address_space(3))) void*)l, 16, 0, 0);
}

// ---------------- elementwise casts ----------------
__global__ void cast_f32_bf16(const float* __restrict__ in, short* __restrict__ out, int n){
  int i = (blockIdx.x * 256 + threadIdx.x) * 4;
  if (i < n){
    float4 v = *(const float4*)(in + i);
    uint32_t lo = (uint32_t)(uint16_t)f2bf(v.x) | ((uint32_t)(uint16_t)f2bf(v.y) << 16);
    uint32_t hi = (uint32_t)(uint16_t)f2bf(v.z) | ((uint32_t)(uint16_t)f2bf(v.w) << 16);
    *(uint2*)(out + i) = make_uint2(lo, hi);
  }
}

// in f32 [R][C] -> out bf16 at out[c*ostride + roff + r']  (transpose + cast)
// permute!=0: r' permuted within each 32-group to the MFMA k-order
// (j = jt*16+q*4+r -> pos = q*8+jt*4+r) so PV B-frags come straight from QK C-frags.
__global__ void transpose_cast(const float* __restrict__ in, short* __restrict__ out,
                               int R, int C, int ostride, int roff, int permute){
  __shared__ float t[32][33];
  int c0 = blockIdx.x * 32, r0 = blockIdx.y * 32;
  int x = threadIdx.x & 31, y = threadIdx.x >> 5;  // y in 0..7
  #pragma unroll
  for (int it = 0; it < 4; ++it)
    t[y + 8*it][x] = in[(size_t)(r0 + y + 8*it) * C + c0 + x];
  __syncthreads();
  int xp = permute ? (((x >> 2) & 3) * 8 + ((x >> 4) & 1) * 4 + (x & 3)) : x;
  #pragma unroll
  for (int it = 0; it < 4; ++it)
    out[(size_t)(c0 + y + 8*it) * ostride + roff + r0 + xp] = f2bf(t[x][y + 8*it]);
}

// f32 [R][512] -> fp8 e4m3 transposed [512][NC] with the fp8 PV k-order:
// within each 64-j chunk, octet o = q*2 + ks (ks = 32-group), pos = o*8 + jt*4 + r.
// One ds_read_b128 then yields the A-frags for BOTH ks MFMAs of a lane.
__global__ void transpose_cast8(const float* __restrict__ in, unsigned char* __restrict__ out,
                                int C, int ostride){
  __shared__ float t[32][33];
  int c0 = blockIdx.x * 32, r0 = blockIdx.y * 32;
  int x = threadIdx.x & 31, y = threadIdx.x >> 5;
  #pragma unroll
  for (int it = 0; it < 4; ++it)
    t[y + 8*it][x] = in[(size_t)(r0 + y + 8*it) * C + c0 + x];
  __syncthreads();
  int xp = ((x >> 2) & 3) * 16 + ((r0 >> 5) & 1) * 8 + ((x >> 4) & 1) * 4 + (x & 3);
  int cb = r0 & ~63;
  #pragma unroll
  for (int it = 0; it < 4; ++it){
    float v = t[x][y + 8*it];
    out[(size_t)(c0 + y + 8*it) * ostride + cb + xp] =
        (unsigned char)(pk_fp8<false>(v, v, 0u) & 0xffu);
  }
}

__global__ void fill_bias(const float* __restrict__ db1, const float* __restrict__ eb1,
                          const float* __restrict__ qb1, float* __restrict__ b){
  int i = blockIdx.x * 256 + threadIdx.x;
  if (i >= 896) return;
  float v = 0.0f;
  if (i < 512) v = db1[i];
  else if (i < 768) v = eb1[i - 512];
  else if (i < 832) v = qb1[i - 768];
  b[i] = v;
}

// ---------------- GEMM: C[M][N] = A[M][K] @ B[N][K]^T ----------------
// BM=64 BN=128 BK=64, 4 waves as 2x2 of [32m x 64n], 16x16x32 bf16 MFMA.
// modes: 0 = outb = bf16(tanh(c+bias)); 1 = outf = c+bias+res; 3 = outf += scale*c
__global__ __launch_bounds__(256, 2)
void gemm_bt(const short* __restrict__ A, int lda, const short* __restrict__ B, int ldb,
             int K, int mode, const float* __restrict__ bias,
             const float* __restrict__ res, int ldres,
             float* __restrict__ outf, short* __restrict__ outb, int ldo, float scale)
{
  __shared__ __align__(16) short As[64 * 64];
  __shared__ __align__(16) short Bs[128 * 64];
  const int tid = threadIdx.x;
  const int lane = tid & 63, wave = tid >> 6;
  const int wm = wave >> 1, wn = wave & 1;
  const int l16 = lane & 15, q = lane >> 4;
  const size_t i0 = (size_t)blockIdx.y * 64;
  const int n0 = blockIdx.x * 128;
  fx4 acc[2][4] = {};

  for (int k0 = 0; k0 < K; k0 += 64){
    #pragma unroll
    for (int inst = 0; inst < 2; ++inst){              // A tile 64x64 = 8KB
      int ch = inst * 256 + tid;
      int r = ch >> 3, pc = ch & 7;
      int colc = (pc ^ (r & 7)) * 8;
      g2l16(A + (i0 + r) * (size_t)lda + k0 + colc, As + ch * 8);
    }
    #pragma unroll
    for (int inst = 0; inst < 4; ++inst){              // B tile 128x64 = 16KB
      int ch = inst * 256 + tid;
      int r = ch >> 3, pc = ch & 7;
      int colc = (pc ^ (r & 7)) * 8;
      g2l16(B + (size_t)(n0 + r) * (size_t)ldb + k0 + colc, Bs + ch * 8);
    }
    __syncthreads();
    #pragma unroll
    for (int ks = 0; ks < 2; ++ks){
      int k8 = ks * 4 + q;
      bf16x8 af[2], bfr[4];
      #pragma unroll
      for (int mi = 0; mi < 2; ++mi){
        int r = wm * 32 + mi * 16 + l16;
        af[mi] = *(const bf16x8*)(As + r * 64 + ((k8 ^ (r & 7)) << 3));
      }
      #pragma unroll
      for (int ni = 0; ni < 4; ++ni){
        int r = wn * 64 + ni * 16 + l16;
        bfr[ni] = *(const bf16x8*)(Bs + r * 64 + ((k8 ^ (r & 7)) << 3));
      }
      #pragma unroll
      for (int mi = 0; mi < 2; ++mi)
        #pragma unroll
        for (int ni = 0; ni < 4; ++ni)
          acc[mi][ni] = __builtin_amdgcn_mfma_f32_16x16x32_bf16(af[mi], bfr[ni], acc[mi][ni], 0, 0, 0);
    }
    __syncthreads();
  }
  // epilogue: C frag layout col=lane&15 (n), row=q*4+r (m)  [HW-verified R1]
  #pragma unroll
  for (int mi = 0; mi < 2; ++mi){
    #pragma unroll
    for (int ni = 0; ni < 4; ++ni){
      int n = n0 + wn * 64 + ni * 16 + l16;
      float b = bias ? bias[n] : 0.0f;
      #pragma unroll
      for (int r = 0; r < 4; ++r){
        size_t m = i0 + wm * 32 + mi * 16 + q * 4 + r;
        float v = acc[mi][ni][r];
        size_t o = m * (size_t)ldo + n;
        if (mode == 0)      outb[o] = f2bf(tanh_fast(v + b));
        else if (mode == 1) outf[o] = v + b + res[m * (size_t)ldres + n];
        else                outf[o] += v * scale;   // mode 3
      }
    }
  }
}

// ---------------- fused attention (smooth), register-resident P ----------------
// 256 threads, 4 waves = 4 distinct 16-row i-slices; each wave covers the full GT
// range. P_ij = E_j*exp(-sqrt(max(sq_i+sq_j-2*enc_i.enc_j,0)));
// OUT[i][g] = (P@V)/rowsum(P), dual f32 write. V = denoisedT (k-permuted).
// GT=128 -> 512 blocks, 32KB LDS, launch_bounds(256,4): 16 waves/CU. (R2-proven.)
template<int GT, int CH, int MODE, int ISL>
__global__ __launch_bounds__(256, (MODE == 0) ? 4 : 2)
void attn_reg(const short* __restrict__ encA, const short* __restrict__ encJ,
              const short* __restrict__ VTp,
              const float* __restrict__ sq, const float* __restrict__ E,
              float* __restrict__ out0, float* __restrict__ out1,
              short* __restrict__ outb, int ldo)
{
  constexpr int NG  = GT / 16;          // g-tiles per wave
  constexpr int KS  = CH / 32;          // MFMA k-steps per chunk
  constexpr int CPR = CH / 8;           // 16B chunks per LDS row
  constexpr int SH  = (CPR == 4) ? 1 : 0; // bank-spread shift for CH=32 rows
  constexpr int HB  = GT * CH;          // shorts per LDS buffer
  __shared__ __align__(16) short Vl[2 * HB];
  const int tid = threadIdx.x, lane = tid & 63, wave = tid >> 6;
  const int l16 = lane & 15, q = lane >> 4;
  const int ib = blockIdx.y * (64 * ISL) + wave * 16;   // slice s adds s*64
  const int g0 = blockIdx.x * GT;
  const short* Ai = encA + (size_t)blockIdx.z * NC * 32;

  bf16x8 bi[ISL];
  float sqi[ISL], lacc[ISL];
  #pragma unroll
  for (int s = 0; s < ISL; ++s){
    bi[s] = *(const bf16x8*)(Ai + (size_t)(ib + s * 64 + l16) * 32 + q * 8);
    lacc[s] = 0.f;
    sqi[s] = (MODE == 0) ? sq[ib + s * 64 + l16] : 0.f;
  }
  fx4 acc[ISL][NG] = {};
  uint4v bP[ISL][KS], bPn[ISL][KS];

  auto stage = [&](int jc, int buf){
    #pragma unroll
    for (int inst = 0; inst < HB / 2048; ++inst){
      int ch = inst * 256 + tid;
      int r = ch / CPR, pc = ch % CPR;
      int colc = (pc ^ ((r >> SH) & (CPR - 1))) * 8;
      g2l16(VTp + (size_t)(g0 + r) * NC + jc + colc, Vl + buf * HB + ch * 8);
    }
  };
  auto transform = [&](int jb, uint4v (*o)[KS]){
    #pragma unroll
    for (int ks = 0; ks < KS; ++ks){
      uint32_t dw[ISL][4];
      #pragma unroll
      for (int jt = 0; jt < 2; ++jt){
        int j0t = jb + ks * 32 + jt * 16;
        bf16x8 aj = *(const bf16x8*)(encJ + (size_t)(j0t + l16) * 32 + q * 8);
        float4 sqj = {}, Ej = {};
        if (MODE == 0){
          sqj = *(const float4*)(sq + j0t + q * 4);
          Ej  = *(const float4*)(E  + j0t + q * 4);
        }
        #pragma unroll
        for (int s = 0; s < ISL; ++s){
          fx4 c = {};
          c = __builtin_amdgcn_mfma_f32_16x16x32_bf16(aj, bi[s], c, 0, 0, 0);
          float pv[4];
          #pragma unroll
          for (int r = 0; r < 4; ++r){
            float dot = c[r];
            if (MODE == 0){
              float d2 = fmaxf(sqi[s] + ((const float*)&sqj)[r] - 2.0f * dot, 0.0f);
              float p = ((const float*)&Ej)[r] * __expf(-fast_sqrt(d2));
              lacc[s] += p;
              pv[r] = p;
            } else {
              pv[r] = fast_rcp(1.0f + __expf(-dot));
            }
          }
          dw[s][jt * 2]     = pack_bf(pv[0], pv[1]);
          dw[s][jt * 2 + 1] = pack_bf(pv[2], pv[3]);
        }
      }
      #pragma unroll
      for (int s = 0; s < ISL; ++s){
        uint4v u = { dw[s][0], dw[s][1], dw[s][2], dw[s][3] };
        o[s][ks] = u;
      }
    }
  };
  auto pv_step = [&](int buf){
    #pragma unroll
    for (int ks = 0; ks < KS; ++ks){
      int k8 = ks * 4 + q;
      #pragma unroll
      for (int gt = 0; gt < NG; ++gt){
        int rr = gt * 16 + l16;
        bf16x8 av = *(const bf16x8*)(Vl + buf * HB + rr * CH +
                                     ((k8 ^ ((rr >> SH) & (CPR - 1))) << 3));
        #pragma unroll
        for (int s = 0; s < ISL; ++s)
          acc[s][gt] = __builtin_amdgcn_mfma_f32_16x16x32_bf16(
              av, *(const bf16x8*)&bP[s][ks], acc[s][gt], 0, 0, 0);
      }
    }
  };

  stage(0, 0);
  transform(0, bP);
  __syncthreads();                       // DMA(0) drained (vmcnt before barrier)
  for (int jc = 0; jc < NC; jc += CH){
    int buf = (jc / CH) & 1;
    int nxt = jc + CH;
    if (nxt < NC){
      stage(nxt, buf ^ 1);               // DMA into other buffer (safe: barrier'd last iter)
      transform(nxt, bPn);               // VALU — interleaves with PV MFMAs below
    }
    pv_step(buf);
    #pragma unroll
    for (int s = 0; s < ISL; ++s)
      #pragma unroll
      for (int ks = 0; ks < KS; ++ks) bP[s][ks] = bPn[s][ks];
    if (nxt < NC) __syncthreads();       // PV(jc) reads done + DMA(nxt) drained
  }

  // epilogue: D frag col = i (l16), row = g (q*4+r)
  #pragma unroll
  for (int s = 0; s < ISL; ++s){
    int irow = ib + s * 64 + l16;
    if (MODE == 0){
      float v = lacc[s];                 // reduce over the 4 q-lanes of this i-row
      v += __shfl_xor(v, 16);
      v += __shfl_xor(v, 32);
      float inv = fast_rcp(v);
      #pragma unroll
      for (int gt = 0; gt < NG; ++gt){
        int g = g0 + gt * 16 + q * 4;
        float4 o;
        o.x = acc[s][gt][0] * inv; o.y = acc[s][gt][1] * inv;
        o.z = acc[s][gt][2] * inv; o.w = acc[s][gt][3] * inv;
        size_t off = (size_t)irow * GG + g;
        *(float4*)(out0 + off) = o;
        *(float4*)(out1 + off) = o;
      }
    } else {
      #pragma unroll
      for (int gt = 0; gt < NG; ++gt){
        int g = g0 + gt * 16 + q * 4;
        uint2 u;
        u.x = pack_bf(acc[s][gt][0], acc[s][gt][1]);
        u.y = pack_bf(acc[s][gt][2], acc[s][gt][3]);
        *(uint2*)(outb + (size_t)irow * ldo + (size_t)blockIdx.z * GG + g) = u;
      }
    }
  }
}

// ---------------- heads attention, fp8 PV, g-partitioned waves + P via LDS (R8) ----------------
// R7 counters: MFMA 42 + VALU 33 = 75% -> 25% stall. LDS-pipe arithmetic: every
// wave read the FULL 512-row V tile (32 b128 = 32KB/wave/chunk) -> 256KB/CU/chunk
// ~= 1000cy at 256B/cy > MFMA ~850cy: LDS READ PORT was the critical pipe, and
// the 4 waves' reads were IDENTICAL (redundant).
// R8: waves own disjoint g-quarters (128 rows); each wave still transforms its own
// i-tile (sigmoid dup stays 1) but publishes the P B-frags through a dbuf 8KB LDS
// buffer (per-lane verbatim uint4v, scheme functionally validated in R6; fp8 pack
// = both ks in one 16B so a single ds_read_b128 carries both k-steps).
// Per wave/chunk: 12 LDS reads (8 V + 4 P) vs R7's 32; MFMA/VALU/stage/barriers/
// V-layout/grid all unchanged from R7 (the only schedule that survived R3/R4/R6).
// LDS: V 64KB + P 8KB = 72KB -> 2 blk/CU.
__global__ __launch_bounds__(256, 2)
void attn_f8(const short* __restrict__ encA, const short* __restrict__ encJ,
             const unsigned char* __restrict__ V8, short* __restrict__ outb, int ldo)
{
  __shared__ __align__(16) unsigned char Vl[2 * 512 * 64];   // 64 KB dbuf
  __shared__ __align__(16) unsigned char Pl[2 * 4096];       // 8 KB dbuf: [it][q][l16] 16B
  const int tid = threadIdx.x, lane = tid & 63, wave = tid >> 6;
  const int l16 = lane & 15, q = lane >> 4;
  const int i0 = blockIdx.y * 64;        // block = 64 i-rows x full 512 g
  const short* Ai = encA + (size_t)blockIdx.z * NC * 32;
  // this wave transforms i-tile `wave`, computes PV for g-quarter wave*128
  const bf16x8 bi = *(const bf16x8*)(Ai + (size_t)(i0 + wave * 16 + l16) * 32 + q * 8);
  fx4 acc[4][8] = {};                    // [i-tile][g-tile]

  auto stage = [&](int jc, int buf){
    #pragma unroll
    for (int inst = 0; inst < 8; ++inst){
      int ch = inst * 256 + tid;          // 16B units, 0..2047
      int r = ch >> 2, pc = ch & 3;       // r = g-row 0..511
      int colc = (pc ^ ((r >> 1) & 3)) * 16;
      g2l16(V8 + (size_t)r * NC + jc + colc, Vl + buf * 32768 + ch * 16);
    }
  };
  // QK (bf16) + sigmoid -> fp8 B-frags for i-tile `wave`; one 16B LDS write holds
  // ks=0 (bytes 0..7) and ks=1 (bytes 8..15) for lane (l16,q). k-order matches the
  // V permute baked by transpose_cast8 (R7-verified).
  auto transform = [&](int jb, int buf){
    uint32_t dwa[2][2];
    #pragma unroll
    for (int ks = 0; ks < 2; ++ks){
      #pragma unroll
      for (int jt = 0; jt < 2; ++jt){
        int j0t = jb + ks * 32 + jt * 16;
        bf16x8 aj = *(const bf16x8*)(encJ + (size_t)(j0t + l16) * 32 + q * 8);
        fx4 c = {};
        c = __builtin_amdgcn_mfma_f32_16x16x32_bf16(aj, bi, c, 0, 0, 0);
        float p[4];
        #pragma unroll
        for (int r = 0; r < 4; ++r)
          p[r] = fast_rcp(1.0f + __expf(-c[r]));
        dwa[ks][jt] = pk_fp8<true>(p[2], p[3], pk_fp8<false>(p[0], p[1], 0u));
      }
    }
    uint4v u = { dwa[0][0], dwa[0][1], dwa[1][0], dwa[1][1] };
    *(uint4v*)(Pl + buf * 4096 + ((wave * 4 + q) * 16 + l16) * 16) = u;
  };
  // PV for g-quarter `wave`, all 4 i-tiles: 4 P b128 + 8 V b128 reads, 64 MFMA.
  auto pv_step = [&](int buf){
    llx2 pf[4];
    #pragma unroll
    for (int it = 0; it < 4; ++it)
      pf[it] = *(const llx2*)(Pl + buf * 4096 + ((it * 4 + q) * 16 + l16) * 16);
    #pragma unroll
    for (int gt = 0; gt < 8; ++gt){
      int rr = wave * 128 + gt * 16 + l16;
      llx2 av = *(const llx2*)(Vl + buf * 32768 + rr * 64 + ((q ^ ((rr >> 1) & 3)) << 4));
      #pragma unroll
      for (int it = 0; it < 4; ++it){
        acc[it][gt] = __builtin_amdgcn_mfma_f32_16x16x32_fp8_fp8(av[0], pf[it][0], acc[it][gt], 0, 0, 0);
        acc[it][gt] = __builtin_amdgcn_mfma_f32_16x16x32_fp8_fp8(av[1], pf[it][1], acc[it][gt], 0, 0, 0);
      }
    }
  };

  stage(0, 0);
  transform(0, 0);
  __syncthreads();                       // V(0) DMA drained + P(0) written
  for (int jc = 0; jc < NC; jc += 64){
    int buf = (jc >> 6) & 1;
    int nxt = jc + 64;
    if (nxt < NC){
      stage(nxt, buf ^ 1);               // DMA into other V buffer
      transform(nxt, buf ^ 1);           // VALU + P(nxt) into other P buffer
    }
    pv_step(buf);
    if (nxt < NC) __syncthreads();       // PV(jc) reads done + V/P(nxt) ready
  }

  // epilogue: D frag col = i (l16), row = g (q*4+r)
  #pragma unroll
  for (int it = 0; it < 4; ++it){
    int irow = i0 + it * 16 + l16;
    #pragma unroll
    for (int gt = 0; gt < 8; ++gt){
      int g = wave * 128 + gt * 16 + q * 4;
      uint2 u;
      u.x = pack_bf(acc[it][gt][0], acc[it][gt][1]);
      u.y = pack_bf(acc[it][gt][2], acc[it][gt][3]);
      *(uint2*)(outb + (size_t)irow * ldo + (size_t)blockIdx.z * GG + g) = u;
    }
  }
}

// ---------------- small MLP tails ----------------
// enc = Hc[:,0:256] @ eW2 + eb2 (bf16-rounded), sq = |enc|^2, Ah[h] = enc @ T[h]
__global__ void embed2_kernel(const short* __restrict__ H2, int lda,
                              const float* __restrict__ eW2,
                              const float* __restrict__ eb2, const float* __restrict__ T4,
                              short* __restrict__ encb, float* __restrict__ sq,
                              short* __restrict__ Ah)
{
  __shared__ float encS[8][32];
  int d = threadIdx.x & 31, cl = threadIdx.x >> 5;
  size_t c = (size_t)blockIdx.x * 8 + cl;
  float s = eb2[d];
  const short* hrow = H2 + c * lda;
  for (int k = 0; k < 256; ++k) s += bf2f(hrow[k]) * eW2[k * 32 + d];
  short eb = f2bf(s);
  encb[c * 32 + d] = eb;
  encS[cl][d] = bf2f(eb);
  __syncthreads();
  if (d == 0){
    float t = 0;
    for (int k = 0; k < 32; ++k) t += encS[cl][k] * encS[cl][k];
    sq[c] = t;
  }
  #pragma unroll
  for (int h = 0; h < 4; ++h){
    float a = 0;
    const float* T = T4 + h * 1024;
    for (int k = 0; k < 32; ++k) a += encS[cl][k] * T[k * 32 + d];
    Ah[(size_t)h * NC * 32 + c * 32 + d] = f2bf(a);
  }
}

// E[c] = exp(Hq[c,:64] . qW2 + qb2)   (tanh already applied by GEMM1)
__global__ void qtail_kernel(const short* __restrict__ Hq, int lda,
                             const float* __restrict__ qW2, const float* __restrict__ qb2,
                             float* __restrict__ E)
{
  int j = threadIdx.x & 63, cl = threadIdx.x >> 6;
  size_t c = (size_t)blockIdx.x * 4 + cl;
  float t = bf2f(Hq[c * lda + j]) * qW2[j];
  #pragma unroll
  for (int o = 32; o >= 1; o >>= 1) t += __shfl_xor(t, o);
  if (j == 0) E[c] = __expf(t + qb2[0]);
}

// ---------------- host ----------------
extern "C" void kernel_launch(void* const* d_in, const int* in_sizes, int n_in,
                              void* d_out, int out_size, void* d_ws, size_t ws_size,
                              hipStream_t stream)
{
  const float* raw = (const float*)d_in[0];
  const float* dW1 = (const float*)d_in[1];
  const float* db1 = (const float*)d_in[2];
  const float* dW2 = (const float*)d_in[3];
  const float* db2 = (const float*)d_in[4];
  const float* eW1 = (const float*)d_in[5];
  const float* eb1 = (const float*)d_in[6];
  const float* eW2 = (const float*)d_in[7];
  const float* eb2 = (const float*)d_in[8];
  const float* qW1 = (const float*)d_in[9];
  const float* qb1 = (const float*)d_in[10];
  const float* qW2 = (const float*)d_in[11];
  const float* qb2 = (const float*)d_in[12];
  const float* Tr  = (const float*)d_in[13];
  const float* Gr  = (const float*)d_in[14];

  float* outD = (float*)d_out;                    // denoised [8192][512]
  float* outS = outD + (size_t)NC * GG;           // smoothed
  float* outF = outS + (size_t)NC * GG;           // final

  char* ws = (char*)d_ws;
  size_t off = 0;
  auto take = [&](size_t bytes) -> char* {
    char* p = ws + off; off += (bytes + 255) & ~(size_t)255; return p;
  };
  short* Xb    = (short*)take((size_t)NC * GG * 2);       // raw bf16
  short* WcatT = (short*)take((size_t)896 * 512 * 2);     // [dW1|eW1|qW1]^T, rows 832..895 pad
  short* dW2T  = (short*)take((size_t)512 * 512 * 2);
  short* GTc   = (short*)take((size_t)512 * 2048 * 2);    // gene_responses^T concat
  float* bcat  = (float*)take((size_t)896 * 4);
  short* Hcat  = (short*)take((size_t)NC * 896 * 2);      // tanh hidden concat [cell][896]
  short* denTp = (short*)take((size_t)GG * NC * 2);       // denoised^T, k-permuted
  unsigned char* smoT8 = (unsigned char*)take((size_t)GG * NC);  // smoothed^T fp8, k-permuted
  short* encb  = (short*)take((size_t)NC * 32 * 2);
  short* Ahb   = (short*)take((size_t)4 * NC * 32 * 2);
  float* sqv   = (float*)take((size_t)NC * 4);
  float* Ev    = (float*)take((size_t)NC * 4);
  short* Ucat  = (short*)take((size_t)NC * 2048 * 2);     // head outputs concat

  dim3 b256(256);
  // ---- casts / transposed weights / bias concat ----
  cast_f32_bf16<<<dim3((NC * GG) / 1024), b256, 0, stream>>>(raw, Xb, NC * GG);
  transpose_cast<<<dim3(16, 16), b256, 0, stream>>>(dW1, WcatT, 512, 512, 512, 0, 0);
  transpose_cast<<<dim3(8, 16),  b256, 0, stream>>>(eW1, WcatT + 512 * 512, 512, 256, 512, 0, 0);
  transpose_cast<<<dim3(2, 16),  b256, 0, stream>>>(qW1, WcatT + 768 * 512, 512, 64, 512, 0, 0);
  transpose_cast<<<dim3(16, 16), b256, 0, stream>>>(dW2, dW2T, 512, 512, 512, 0, 0);
  for (int h = 0; h < 4; ++h)
    transpose_cast<<<dim3(16, 16), b256, 0, stream>>>(Gr + (size_t)h * 512 * 512,
                                                      GTc, 512, 512, 2048, h * 512, 0);
  fill_bias<<<dim3(4), b256, 0, stream>>>(db1, eb1, qb1, bcat);
  // ---- fused first layer: Hcat = tanh(X @ [dW1|eW1|qW1] + bcat)  (N=896) ----
  gemm_bt<<<dim3(7, 128), b256, 0, stream>>>(Xb, 512, WcatT, 512, 512, 0, bcat,
                                             (const float*)nullptr, 0,
                                             (float*)nullptr, Hcat, 896, 1.0f);
  // ---- denoise layer 2: outD = Hcat[:,0:512] @ dW2 + db2 + raw ----
  gemm_bt<<<dim3(4, 128), b256, 0, stream>>>(Hcat, 896, dW2T, 512, 512, 1, db2,
                                             raw, 512, outD, (short*)nullptr, 512, 1.0f);
  transpose_cast<<<dim3(16, 256), b256, 0, stream>>>(outD, denTp, NC, 512, NC, 0, 1);
  // ---- embed tail + quality tail ----
  embed2_kernel<<<dim3(NC / 8), b256, 0, stream>>>(Hcat + 512, 896, eW2, eb2, Tr,
                                                   encb, sqv, Ahb);
  qtail_kernel<<<dim3(NC / 4), b256, 0, stream>>>(Hcat + 768, 896, qW2, qb2, Ev);
  // ---- fused smooth: outS = outF = softmax-weighted avg of denoised ----
  attn_reg<128, 64, 0, 1><<<dim3(4, 128, 1), b256, 0, stream>>>(
      encb, encb, denTp, sqv, Ev, outS, outF, (short*)nullptr, 0);
  transpose_cast8<<<dim3(16, 256), b256, 0, stream>>>(outS, smoT8, 512, NC);
  // ---- fused heads: Ucat[:, h*512:] = sigmoid(Ah_h enc^T) @ smoothed ----
  // fp8 V/P, g-partitioned waves, P through LDS: 12 LDS reads/wave/chunk (was 32)
  attn_f8<<<dim3(1, 128, 4), b256, 0, stream>>>(Ahb, encb, smoT8, Ucat, 2048);
  // ---- final += (Ucat @ GTcat^T) / N   (single K=2048 GEMM) ----
  gemm_bt<<<dim3(4, 128), b256, 0, stream>>>(Ucat, 2048, GTc, 2048, 2048,
                                             3, (const float*)nullptr,
                                             (const float*)nullptr, 0,
                                             outF, (short*)nullptr, 512, 1.0f / NC);
}

// Round 9
// 675.857 us; speedup vs baseline: 1.3910x; 1.0665x over previous
//
#include <hip/hip_runtime.h>
#include <hip/hip_bf16.h>
#include <stdint.h>
#if !__has_builtin(__builtin_amdgcn_cvt_pk_fp8_f32)
#include <hip/hip_fp8.h>
#endif

#define NC 8192
#define GG 512

typedef __attribute__((ext_vector_type(8))) short bf16x8;   // 8 bf16 = 4 VGPRs (MFMA A/B frag)
typedef __attribute__((ext_vector_type(4))) float fx4;      // MFMA C/D frag
typedef __attribute__((ext_vector_type(4))) unsigned int uint4v;
typedef __attribute__((ext_vector_type(2))) long long llx2; // 16B = two fp8 A/B-frags

__device__ __forceinline__ float bf2f(short s){
  union { uint32_t u; float f; } c; c.u = ((uint32_t)(uint16_t)s) << 16; return c.f;
}
__device__ __forceinline__ short f2bf(float f){
  union { float f; uint32_t u; } c; c.f = f;
  uint32_t u = c.u;
  uint32_t r = (u + 0x7fffu + ((u >> 16) & 1u)) >> 16;   // RNE
  return (short)(uint16_t)r;
}
__device__ __forceinline__ uint32_t au(float f){
  union { float f; uint32_t u; } c; c.f = f; return c.u;
}
#if __has_builtin(__builtin_amdgcn_rcpf)
__device__ __forceinline__ float fast_rcp(float x){ return __builtin_amdgcn_rcpf(x); }
#else
__device__ __forceinline__ float fast_rcp(float x){ return 1.0f / x; }
#endif
#if __has_builtin(__builtin_amdgcn_sqrtf)
__device__ __forceinline__ float fast_sqrt(float x){ return __builtin_amdgcn_sqrtf(x); }
#else
__device__ __forceinline__ float fast_sqrt(float x){ return sqrtf(x); }
#endif
__device__ __forceinline__ float tanh_fast(float x){      // |err| ~1e-7 rel of rcp: fine at bf16
  float e = __expf(2.0f * x);
  return 1.0f - 2.0f * fast_rcp(e + 1.0f);
}
// pack two floats -> bf16 pair (round-half-up via +0x8000, then byte-perm hi16s)
__device__ __forceinline__ uint32_t pack_bf(float lo, float hi){
  return __builtin_amdgcn_perm(au(hi) + 0x8000u, au(lo) + 0x8000u, 0x07060302u);
}
// pack two floats -> 2 x fp8 e4m3 (OCP on gfx950) into lo/hi half of a dword
template<bool HI>
__device__ __forceinline__ uint32_t pk_fp8(float a, float b, uint32_t old){
#if __has_builtin(__builtin_amdgcn_cvt_pk_fp8_f32)
  return (uint32_t)__builtin_amdgcn_cvt_pk_fp8_f32(a, b, (int)old, HI);
#else
  __hip_fp8_e4m3 fa(a), fb(b);
  uint32_t v = (uint32_t)fa.__x | ((uint32_t)fb.__x << 8);
  return HI ? ((old & 0x0000ffffu) | (v << 16)) : ((old & 0xffff0000u) | v);
#endif
}
__device__ __forceinline__ void g2l16(const void* g, void* l){
  __builtin_amdgcn_global_load_lds((const __attribute__((address_space(1))) void*)g,
                                   (__attribute__((address_space(3))) void*)l, 16, 0, 0);
}

// ---------------- elementwise casts ----------------
__global__ void cast_f32_bf16(const float* __restrict__ in, short* __restrict__ out, int n){
  int i = (blockIdx.x * 256 + threadIdx.x) * 4;
  if (i < n){
    float4 v = *(const float4*)(in + i);
    uint32_t lo = (uint32_t)(uint16_t)f2bf(v.x) | ((uint32_t)(uint16_t)f2bf(v.y) << 16);
    uint32_t hi = (uint32_t)(uint16_t)f2bf(v.z) | ((uint32_t)(uint16_t)f2bf(v.w) << 16);
    *(uint2*)(out + i) = make_uint2(lo, hi);
  }
}

// combine the two j-half partials of the smooth attention:
// out = (Po[0] + Po[1]) * rcp(L[0] + L[1]), dual write (outS, outF)
__global__ void combine_smooth(const float* __restrict__ Po, const float* __restrict__ Ls,
                               float* __restrict__ out0, float* __restrict__ out1){
  size_t idx = ((size_t)blockIdx.x * 256 + threadIdx.x) * 4;
  float4 a = *(const float4*)(Po + idx);
  float4 b = *(const float4*)(Po + (size_t)NC * GG + idx);
  int row = (int)(idx >> 9);
  float inv = fast_rcp(Ls[row] + Ls[NC + row]);
  float4 o;
  o.x = (a.x + b.x) * inv; o.y = (a.y + b.y) * inv;
  o.z = (a.z + b.z) * inv; o.w = (a.w + b.w) * inv;
  *(float4*)(out0 + idx) = o;
  *(float4*)(out1 + idx) = o;
}

// in f32 [R][C] -> out bf16 at out[c*ostride + roff + r']  (transpose + cast)
// permute!=0: r' permuted within each 32-group to the MFMA k-order
// (j = jt*16+q*4+r -> pos = q*8+jt*4+r) so PV B-frags come straight from QK C-frags.
__global__ void transpose_cast(const float* __restrict__ in, short* __restrict__ out,
                               int R, int C, int ostride, int roff, int permute){
  __shared__ float t[32][33];
  int c0 = blockIdx.x * 32, r0 = blockIdx.y * 32;
  int x = threadIdx.x & 31, y = threadIdx.x >> 5;  // y in 0..7
  #pragma unroll
  for (int it = 0; it < 4; ++it)
    t[y + 8*it][x] = in[(size_t)(r0 + y + 8*it) * C + c0 + x];
  __syncthreads();
  int xp = permute ? (((x >> 2) & 3) * 8 + ((x >> 4) & 1) * 4 + (x & 3)) : x;
  #pragma unroll
  for (int it = 0; it < 4; ++it)
    out[(size_t)(c0 + y + 8*it) * ostride + roff + r0 + xp] = f2bf(t[x][y + 8*it]);
}

// f32 [R][512] -> fp8 e4m3 transposed [512][NC] with the fp8 PV k-order:
// within each 64-j chunk, octet o = q*2 + ks (ks = 32-group), pos = o*8 + jt*4 + r.
// One ds_read_b128 then yields the A-frags for BOTH ks MFMAs of a lane.
__global__ void transpose_cast8(const float* __restrict__ in, unsigned char* __restrict__ out,
                                int C, int ostride){
  __shared__ float t[32][33];
  int c0 = blockIdx.x * 32, r0 = blockIdx.y * 32;
  int x = threadIdx.x & 31, y = threadIdx.x >> 5;
  #pragma unroll
  for (int it = 0; it < 4; ++it)
    t[y + 8*it][x] = in[(size_t)(r0 + y + 8*it) * C + c0 + x];
  __syncthreads();
  int xp = ((x >> 2) & 3) * 16 + ((r0 >> 5) & 1) * 8 + ((x >> 4) & 1) * 4 + (x & 3);
  int cb = r0 & ~63;
  #pragma unroll
  for (int it = 0; it < 4; ++it){
    float v = t[x][y + 8*it];
    out[(size_t)(c0 + y + 8*it) * ostride + cb + xp] =
        (unsigned char)(pk_fp8<false>(v, v, 0u) & 0xffu);
  }
}

__global__ void fill_bias(const float* __restrict__ db1, const float* __restrict__ eb1,
                          const float* __restrict__ qb1, float* __restrict__ b){
  int i = blockIdx.x * 256 + threadIdx.x;
  if (i >= 896) return;
  float v = 0.0f;
  if (i < 512) v = db1[i];
  else if (i < 768) v = eb1[i - 512];
  else if (i < 832) v = qb1[i - 768];
  b[i] = v;
}

// ---------------- GEMM: C[M][N] = A[M][K] @ B[N][K]^T ----------------
// BM=64 BN=128 BK=64, 4 waves as 2x2 of [32m x 64n], 16x16x32 bf16 MFMA.
// modes: 0 = outb = bf16(tanh(c+bias)); 1 = outf = c+bias+res; 3 = outf += scale*c
__global__ __launch_bounds__(256, 2)
void gemm_bt(const short* __restrict__ A, int lda, const short* __restrict__ B, int ldb,
             int K, int mode, const float* __restrict__ bias,
             const float* __restrict__ res, int ldres,
             float* __restrict__ outf, short* __restrict__ outb, int ldo, float scale)
{
  __shared__ __align__(16) short As[64 * 64];
  __shared__ __align__(16) short Bs[128 * 64];
  const int tid = threadIdx.x;
  const int lane = tid & 63, wave = tid >> 6;
  const int wm = wave >> 1, wn = wave & 1;
  const int l16 = lane & 15, q = lane >> 4;
  const size_t i0 = (size_t)blockIdx.y * 64;
  const int n0 = blockIdx.x * 128;
  fx4 acc[2][4] = {};

  for (int k0 = 0; k0 < K; k0 += 64){
    #pragma unroll
    for (int inst = 0; inst < 2; ++inst){              // A tile 64x64 = 8KB
      int ch = inst * 256 + tid;
      int r = ch >> 3, pc = ch & 7;
      int colc = (pc ^ (r & 7)) * 8;
      g2l16(A + (i0 + r) * (size_t)lda + k0 + colc, As + ch * 8);
    }
    #pragma unroll
    for (int inst = 0; inst < 4; ++inst){              // B tile 128x64 = 16KB
      int ch = inst * 256 + tid;
      int r = ch >> 3, pc = ch & 7;
      int colc = (pc ^ (r & 7)) * 8;
      g2l16(B + (size_t)(n0 + r) * (size_t)ldb + k0 + colc, Bs + ch * 8);
    }
    __syncthreads();
    #pragma unroll
    for (int ks = 0; ks < 2; ++ks){
      int k8 = ks * 4 + q;
      bf16x8 af[2], bfr[4];
      #pragma unroll
      for (int mi = 0; mi < 2; ++mi){
        int r = wm * 32 + mi * 16 + l16;
        af[mi] = *(const bf16x8*)(As + r * 64 + ((k8 ^ (r & 7)) << 3));
      }
      #pragma unroll
      for (int ni = 0; ni < 4; ++ni){
        int r = wn * 64 + ni * 16 + l16;
        bfr[ni] = *(const bf16x8*)(Bs + r * 64 + ((k8 ^ (r & 7)) << 3));
      }
      #pragma unroll
      for (int mi = 0; mi < 2; ++mi)
        #pragma unroll
        for (int ni = 0; ni < 4; ++ni)
          acc[mi][ni] = __builtin_amdgcn_mfma_f32_16x16x32_bf16(af[mi], bfr[ni], acc[mi][ni], 0, 0, 0);
    }
    __syncthreads();
  }
  // epilogue: C frag layout col=lane&15 (n), row=q*4+r (m)  [HW-verified R1]
  #pragma unroll
  for (int mi = 0; mi < 2; ++mi){
    #pragma unroll
    for (int ni = 0; ni < 4; ++ni){
      int n = n0 + wn * 64 + ni * 16 + l16;
      float b = bias ? bias[n] : 0.0f;
      #pragma unroll
      for (int r = 0; r < 4; ++r){
        size_t m = i0 + wm * 32 + mi * 16 + q * 4 + r;
        float v = acc[mi][ni][r];
        size_t o = m * (size_t)ldo + n;
        if (mode == 0)      outb[o] = f2bf(tanh_fast(v + b));
        else if (mode == 1) outf[o] = v + b + res[m * (size_t)ldres + n];
        else                outf[o] += v * scale;   // mode 3
      }
    }
  }
}

// ---------------- fused attention (smooth), register-resident P, j-split (R9) ----------------
// 256 threads, 4 waves = 4 distinct 16-row i-slices; each wave covers the full GT
// range. P_ij = E_j*exp(-sqrt(max(sq_i+sq_j-2*enc_i.enc_j,0))).
// R9: smooth was GRID-LIMITED to 2 blk/CU (512 blocks; VGPR 48 + LDS 32KB allow 4)
// with busy-sum only 49% -> per-chunk drain latency exposed, too few waves to hide.
// j is a pure sum, so split it across blockIdx.z (2 halves): 1024 blocks = 4 blk/CU,
// 16 waves/CU. Blocks write PARTIAL O (un-normalized f32) + partial rowsum; a tiny
// combine kernel does (O0+O1)*rcp(l0+l1). Schedule/swizzle/DMA depth unchanged.
// out0 = Po partials [2][NC][GG], out1 = Lsum [2][NC] (gx==0, q==0 lanes write).
template<int GT, int CH, int MODE, int ISL>
__global__ __launch_bounds__(256, (MODE == 0) ? 4 : 2)
void attn_reg(const short* __restrict__ encA, const short* __restrict__ encJ,
              const short* __restrict__ VTp,
              const float* __restrict__ sq, const float* __restrict__ E,
              float* __restrict__ out0, float* __restrict__ out1,
              short* __restrict__ outb, int ldo)
{
  constexpr int NG  = GT / 16;          // g-tiles per wave
  constexpr int KS  = CH / 32;          // MFMA k-steps per chunk
  constexpr int CPR = CH / 8;           // 16B chunks per LDS row
  constexpr int SH  = (CPR == 4) ? 1 : 0; // bank-spread shift for CH=32 rows
  constexpr int HB  = GT * CH;          // shorts per LDS buffer
  __shared__ __align__(16) short Vl[2 * HB];
  const int tid = threadIdx.x, lane = tid & 63, wave = tid >> 6;
  const int l16 = lane & 15, q = lane >> 4;
  const int ib = blockIdx.y * (64 * ISL) + wave * 16;   // slice s adds s*64
  const int g0 = blockIdx.x * GT;
  const short* Ai = encA + (MODE == 1 ? (size_t)blockIdx.z * NC * 32 : (size_t)0);
  const int jlen = NC / (int)gridDim.z;                 // j-range of this block
  const int jbase = (int)blockIdx.z * jlen;

  bf16x8 bi[ISL];
  float sqi[ISL], lacc[ISL];
  #pragma unroll
  for (int s = 0; s < ISL; ++s){
    bi[s] = *(const bf16x8*)(Ai + (size_t)(ib + s * 64 + l16) * 32 + q * 8);
    lacc[s] = 0.f;
    sqi[s] = (MODE == 0) ? sq[ib + s * 64 + l16] : 0.f;
  }
  fx4 acc[ISL][NG] = {};
  uint4v bP[ISL][KS], bPn[ISL][KS];

  auto stage = [&](int jc, int buf){
    #pragma unroll
    for (int inst = 0; inst < HB / 2048; ++inst){
      int ch = inst * 256 + tid;
      int r = ch / CPR, pc = ch % CPR;
      int colc = (pc ^ ((r >> SH) & (CPR - 1))) * 8;
      g2l16(VTp + (size_t)(g0 + r) * NC + jc + colc, Vl + buf * HB + ch * 8);
    }
  };
  auto transform = [&](int jb, uint4v (*o)[KS]){
    #pragma unroll
    for (int ks = 0; ks < KS; ++ks){
      uint32_t dw[ISL][4];
      #pragma unroll
      for (int jt = 0; jt < 2; ++jt){
        int j0t = jb + ks * 32 + jt * 16;
        bf16x8 aj = *(const bf16x8*)(encJ + (size_t)(j0t + l16) * 32 + q * 8);
        float4 sqj = {}, Ej = {};
        if (MODE == 0){
          sqj = *(const float4*)(sq + j0t + q * 4);
          Ej  = *(const float4*)(E  + j0t + q * 4);
        }
        #pragma unroll
        for (int s = 0; s < ISL; ++s){
          fx4 c = {};
          c = __builtin_amdgcn_mfma_f32_16x16x32_bf16(aj, bi[s], c, 0, 0, 0);
          float pv[4];
          #pragma unroll
          for (int r = 0; r < 4; ++r){
            float dot = c[r];
            if (MODE == 0){
              float d2 = fmaxf(sqi[s] + ((const float*)&sqj)[r] - 2.0f * dot, 0.0f);
              float p = ((const float*)&Ej)[r] * __expf(-fast_sqrt(d2));
              lacc[s] += p;
              pv[r] = p;
            } else {
              pv[r] = fast_rcp(1.0f + __expf(-dot));
            }
          }
          dw[s][jt * 2]     = pack_bf(pv[0], pv[1]);
          dw[s][jt * 2 + 1] = pack_bf(pv[2], pv[3]);
        }
      }
      #pragma unroll
      for (int s = 0; s < ISL; ++s){
        uint4v u = { dw[s][0], dw[s][1], dw[s][2], dw[s][3] };
        o[s][ks] = u;
      }
    }
  };
  auto pv_step = [&](int buf){
    #pragma unroll
    for (int ks = 0; ks < KS; ++ks){
      int k8 = ks * 4 + q;
      #pragma unroll
      for (int gt = 0; gt < NG; ++gt){
        int rr = gt * 16 + l16;
        bf16x8 av = *(const bf16x8*)(Vl + buf * HB + rr * CH +
                                     ((k8 ^ ((rr >> SH) & (CPR - 1))) << 3));
        #pragma unroll
        for (int s = 0; s < ISL; ++s)
          acc[s][gt] = __builtin_amdgcn_mfma_f32_16x16x32_bf16(
              av, *(const bf16x8*)&bP[s][ks], acc[s][gt], 0, 0, 0);
      }
    }
  };

  stage(jbase, 0);
  transform(jbase, bP);
  __syncthreads();                       // DMA(0) drained (vmcnt before barrier)
  for (int t = 0; t < jlen; t += CH){
    int buf = (t / CH) & 1;
    int nt = t + CH;
    if (nt < jlen){
      stage(jbase + nt, buf ^ 1);        // DMA into other buffer (safe: barrier'd last iter)
      transform(jbase + nt, bPn);        // VALU — interleaves with PV MFMAs below
    }
    pv_step(buf);
    #pragma unroll
    for (int s = 0; s < ISL; ++s)
      #pragma unroll
      for (int ks = 0; ks < KS; ++ks) bP[s][ks] = bPn[s][ks];
    if (nt < jlen) __syncthreads();      // PV(t) reads done + DMA(nt) drained
  }

  // epilogue: D frag col = i (l16), row = g (q*4+r)
  #pragma unroll
  for (int s = 0; s < ISL; ++s){
    int irow = ib + s * 64 + l16;
    if (MODE == 0){
      float v = lacc[s];                 // reduce over the 4 q-lanes of this i-row
      v += __shfl_xor(v, 16);
      v += __shfl_xor(v, 32);
      if (g0 == 0 && q == 0) out1[(size_t)blockIdx.z * NC + irow] = v;
      #pragma unroll
      for (int gt = 0; gt < NG; ++gt){
        int g = g0 + gt * 16 + q * 4;
        float4 o;
        o.x = acc[s][gt][0]; o.y = acc[s][gt][1];
        o.z = acc[s][gt][2]; o.w = acc[s][gt][3];
        *(float4*)(out0 + ((size_t)blockIdx.z * NC + irow) * GG + g) = o;
      }
    } else {
      #pragma unroll
      for (int gt = 0; gt < NG; ++gt){
        int g = g0 + gt * 16 + q * 4;
        uint2 u;
        u.x = pack_bf(acc[s][gt][0], acc[s][gt][1]);
        u.y = pack_bf(acc[s][gt][2], acc[s][gt][3]);
        *(uint2*)(outb + (size_t)irow * ldo + (size_t)blockIdx.z * GG + g) = u;
      }
    }
  }
}

// ---------------- heads attention, fp8 PV, g-partitioned waves + P via LDS (R8) ----------------
// R7 counters: MFMA 42 + VALU 33 = 75% -> 25% stall; LDS read port was the critical
// pipe (4 waves redundantly reading the full V tile). R8: waves own disjoint
// g-quarters; each wave transforms its own i-tile and publishes fp8 P B-frags via a
// dbuf 8KB LDS buffer (both ks packed in one 16B -> one ds_read_b128 per P frag).
// 12 LDS reads/wave/chunk (was 32). Verified: heads ~230us (R8 bench).
__global__ __launch_bounds__(256, 2)
void attn_f8(const short* __restrict__ encA, const short* __restrict__ encJ,
             const unsigned char* __restrict__ V8, short* __restrict__ outb, int ldo)
{
  __shared__ __align__(16) unsigned char Vl[2 * 512 * 64];   // 64 KB dbuf
  __shared__ __align__(16) unsigned char Pl[2 * 4096];       // 8 KB dbuf: [it][q][l16] 16B
  const int tid = threadIdx.x, lane = tid & 63, wave = tid >> 6;
  const int l16 = lane & 15, q = lane >> 4;
  const int i0 = blockIdx.y * 64;        // block = 64 i-rows x full 512 g
  const short* Ai = encA + (size_t)blockIdx.z * NC * 32;
  // this wave transforms i-tile `wave`, computes PV for g-quarter wave*128
  const bf16x8 bi = *(const bf16x8*)(Ai + (size_t)(i0 + wave * 16 + l16) * 32 + q * 8);
  fx4 acc[4][8] = {};                    // [i-tile][g-tile]

  auto stage = [&](int jc, int buf){
    #pragma unroll
    for (int inst = 0; inst < 8; ++inst){
      int ch = inst * 256 + tid;          // 16B units, 0..2047
      int r = ch >> 2, pc = ch & 3;       // r = g-row 0..511
      int colc = (pc ^ ((r >> 1) & 3)) * 16;
      g2l16(V8 + (size_t)r * NC + jc + colc, Vl + buf * 32768 + ch * 16);
    }
  };
  // QK (bf16) + sigmoid -> fp8 B-frags for i-tile `wave`; one 16B LDS write holds
  // ks=0 (bytes 0..7) and ks=1 (bytes 8..15) for lane (l16,q). k-order matches the
  // V permute baked by transpose_cast8 (R7-verified).
  auto transform = [&](int jb, int buf){
    uint32_t dwa[2][2];
    #pragma unroll
    for (int ks = 0; ks < 2; ++ks){
      #pragma unroll
      for (int jt = 0; jt < 2; ++jt){
        int j0t = jb + ks * 32 + jt * 16;
        bf16x8 aj = *(const bf16x8*)(encJ + (size_t)(j0t + l16) * 32 + q * 8);
        fx4 c = {};
        c = __builtin_amdgcn_mfma_f32_16x16x32_bf16(aj, bi, c, 0, 0, 0);
        float p[4];
        #pragma unroll
        for (int r = 0; r < 4; ++r)
          p[r] = fast_rcp(1.0f + __expf(-c[r]));
        dwa[ks][jt] = pk_fp8<true>(p[2], p[3], pk_fp8<false>(p[0], p[1], 0u));
      }
    }
    uint4v u = { dwa[0][0], dwa[0][1], dwa[1][0], dwa[1][1] };
    *(uint4v*)(Pl + buf * 4096 + ((wave * 4 + q) * 16 + l16) * 16) = u;
  };
  // PV for g-quarter `wave`, all 4 i-tiles: 4 P b128 + 8 V b128 reads, 64 MFMA.
  auto pv_step = [&](int buf){
    llx2 pf[4];
    #pragma unroll
    for (int it = 0; it < 4; ++it)
      pf[it] = *(const llx2*)(Pl + buf * 4096 + ((it * 4 + q) * 16 + l16) * 16);
    #pragma unroll
    for (int gt = 0; gt < 8; ++gt){
      int rr = wave * 128 + gt * 16 + l16;
      llx2 av = *(const llx2*)(Vl + buf * 32768 + rr * 64 + ((q ^ ((rr >> 1) & 3)) << 4));
      #pragma unroll
      for (int it = 0; it < 4; ++it){
        acc[it][gt] = __builtin_amdgcn_mfma_f32_16x16x32_fp8_fp8(av[0], pf[it][0], acc[it][gt], 0, 0, 0);
        acc[it][gt] = __builtin_amdgcn_mfma_f32_16x16x32_fp8_fp8(av[1], pf[it][1], acc[it][gt], 0, 0, 0);
      }
    }
  };

  stage(0, 0);
  transform(0, 0);
  __syncthreads();                       // V(0) DMA drained + P(0) written
  for (int jc = 0; jc < NC; jc += 64){
    int buf = (jc >> 6) & 1;
    int nxt = jc + 64;
    if (nxt < NC){
      stage(nxt, buf ^ 1);               // DMA into other V buffer
      transform(nxt, buf ^ 1);           // VALU + P(nxt) into other P buffer
    }
    pv_step(buf);
    if (nxt < NC) __syncthreads();       // PV(jc) reads done + V/P(nxt) ready
  }

  // epilogue: D frag col = i (l16), row = g (q*4+r)
  #pragma unroll
  for (int it = 0; it < 4; ++it){
    int irow = i0 + it * 16 + l16;
    #pragma unroll
    for (int gt = 0; gt < 8; ++gt){
      int g = wave * 128 + gt * 16 + q * 4;
      uint2 u;
      u.x = pack_bf(acc[it][gt][0], acc[it][gt][1]);
      u.y = pack_bf(acc[it][gt][2], acc[it][gt][3]);
      *(uint2*)(outb + (size_t)irow * ldo + (size_t)blockIdx.z * GG + g) = u;
    }
  }
}

// ---------------- small MLP tails ----------------
// enc = Hc[:,0:256] @ eW2 + eb2 (bf16-rounded), sq = |enc|^2, Ah[h] = enc @ T[h]
__global__ void embed2_kernel(const short* __restrict__ H2, int lda,
                              const float* __restrict__ eW2,
                              const float* __restrict__ eb2, const float* __restrict__ T4,
                              short* __restrict__ encb, float* __restrict__ sq,
                              short* __restrict__ Ah)
{
  __shared__ float encS[8][32];
  int d = threadIdx.x & 31, cl = threadIdx.x >> 5;
  size_t c = (size_t)blockIdx.x * 8 + cl;
  float s = eb2[d];
  const short* hrow = H2 + c * lda;
  for (int k = 0; k < 256; ++k) s += bf2f(hrow[k]) * eW2[k * 32 + d];
  short eb = f2bf(s);
  encb[c * 32 + d] = eb;
  encS[cl][d] = bf2f(eb);
  __syncthreads();
  if (d == 0){
    float t = 0;
    for (int k = 0; k < 32; ++k) t += encS[cl][k] * encS[cl][k];
    sq[c] = t;
  }
  #pragma unroll
  for (int h = 0; h < 4; ++h){
    float a = 0;
    const float* T = T4 + h * 1024;
    for (int k = 0; k < 32; ++k) a += encS[cl][k] * T[k * 32 + d];
    Ah[(size_t)h * NC * 32 + c * 32 + d] = f2bf(a);
  }
}

// E[c] = exp(Hq[c,:64] . qW2 + qb2)   (tanh already applied by GEMM1)
__global__ void qtail_kernel(const short* __restrict__ Hq, int lda,
                             const float* __restrict__ qW2, const float* __restrict__ qb2,
                             float* __restrict__ E)
{
  int j = threadIdx.x & 63, cl = threadIdx.x >> 6;
  size_t c = (size_t)blockIdx.x * 4 + cl;
  float t = bf2f(Hq[c * lda + j]) * qW2[j];
  #pragma unroll
  for (int o = 32; o >= 1; o >>= 1) t += __shfl_xor(t, o);
  if (j == 0) E[c] = __expf(t + qb2[0]);
}

// ---------------- host ----------------
extern "C" void kernel_launch(void* const* d_in, const int* in_sizes, int n_in,
                              void* d_out, int out_size, void* d_ws, size_t ws_size,
                              hipStream_t stream)
{
  const float* raw = (const float*)d_in[0];
  const float* dW1 = (const float*)d_in[1];
  const float* db1 = (const float*)d_in[2];
  const float* dW2 = (const float*)d_in[3];
  const float* db2 = (const float*)d_in[4];
  const float* eW1 = (const float*)d_in[5];
  const float* eb1 = (const float*)d_in[6];
  const float* eW2 = (const float*)d_in[7];
  const float* eb2 = (const float*)d_in[8];
  const float* qW1 = (const float*)d_in[9];
  const float* qb1 = (const float*)d_in[10];
  const float* qW2 = (const float*)d_in[11];
  const float* qb2 = (const float*)d_in[12];
  const float* Tr  = (const float*)d_in[13];
  const float* Gr  = (const float*)d_in[14];

  float* outD = (float*)d_out;                    // denoised [8192][512]
  float* outS = outD + (size_t)NC * GG;           // smoothed
  float* outF = outS + (size_t)NC * GG;           // final

  char* ws = (char*)d_ws;
  size_t off = 0;
  auto take = [&](size_t bytes) -> char* {
    char* p = ws + off; off += (bytes + 255) & ~(size_t)255; return p;
  };
  short* Xb    = (short*)take((size_t)NC * GG * 2);       // raw bf16
  short* WcatT = (short*)take((size_t)896 * 512 * 2);     // [dW1|eW1|qW1]^T, rows 832..895 pad
  short* dW2T  = (short*)take((size_t)512 * 512 * 2);
  short* GTc   = (short*)take((size_t)512 * 2048 * 2);    // gene_responses^T concat
  float* bcat  = (float*)take((size_t)896 * 4);
  short* Hcat  = (short*)take((size_t)NC * 896 * 2);      // tanh hidden concat [cell][896]
  short* denTp = (short*)take((size_t)GG * NC * 2);       // denoised^T, k-permuted
  unsigned char* smoT8 = (unsigned char*)take((size_t)GG * NC);  // smoothed^T fp8, k-permuted
  short* encb  = (short*)take((size_t)NC * 32 * 2);
  short* Ahb   = (short*)take((size_t)4 * NC * 32 * 2);
  float* sqv   = (float*)take((size_t)NC * 4);
  float* Ev    = (float*)take((size_t)NC * 4);
  float* Lsum  = (float*)take((size_t)2 * NC * 4);        // smooth partial rowsums
  short* Ucat  = (short*)take((size_t)NC * 2048 * 2);     // head outputs concat
  // smooth partials [2][NC][GG] f32 alias Ucat's 32MB (Ucat written only later)
  float* Po    = (float*)Ucat;

  dim3 b256(256);
  // ---- casts / transposed weights / bias concat ----
  cast_f32_bf16<<<dim3((NC * GG) / 1024), b256, 0, stream>>>(raw, Xb, NC * GG);
  transpose_cast<<<dim3(16, 16), b256, 0, stream>>>(dW1, WcatT, 512, 512, 512, 0, 0);
  transpose_cast<<<dim3(8, 16),  b256, 0, stream>>>(eW1, WcatT + 512 * 512, 512, 256, 512, 0, 0);
  transpose_cast<<<dim3(2, 16),  b256, 0, stream>>>(qW1, WcatT + 768 * 512, 512, 64, 512, 0, 0);
  transpose_cast<<<dim3(16, 16), b256, 0, stream>>>(dW2, dW2T, 512, 512, 512, 0, 0);
  for (int h = 0; h < 4; ++h)
    transpose_cast<<<dim3(16, 16), b256, 0, stream>>>(Gr + (size_t)h * 512 * 512,
                                                      GTc, 512, 512, 2048, h * 512, 0);
  fill_bias<<<dim3(4), b256, 0, stream>>>(db1, eb1, qb1, bcat);
  // ---- fused first layer: Hcat = tanh(X @ [dW1|eW1|qW1] + bcat)  (N=896) ----
  gemm_bt<<<dim3(7, 128), b256, 0, stream>>>(Xb, 512, WcatT, 512, 512, 0, bcat,
                                             (const float*)nullptr, 0,
                                             (float*)nullptr, Hcat, 896, 1.0f);
  // ---- denoise layer 2: outD = Hcat[:,0:512] @ dW2 + db2 + raw ----
  gemm_bt<<<dim3(4, 128), b256, 0, stream>>>(Hcat, 896, dW2T, 512, 512, 1, db2,
                                             raw, 512, outD, (short*)nullptr, 512, 1.0f);
  transpose_cast<<<dim3(16, 256), b256, 0, stream>>>(outD, denTp, NC, 512, NC, 0, 1);
  // ---- embed tail + quality tail ----
  embed2_kernel<<<dim3(NC / 8), b256, 0, stream>>>(Hcat + 512, 896, eW2, eb2, Tr,
                                                   encb, sqv, Ahb);
  qtail_kernel<<<dim3(NC / 4), b256, 0, stream>>>(Hcat + 768, 896, qW2, qb2, Ev);
  // ---- fused smooth (j-split x2, partial outputs) + combine ----
  attn_reg<128, 64, 0, 1><<<dim3(4, 128, 2), b256, 0, stream>>>(
      encb, encb, denTp, sqv, Ev, Po, Lsum, (short*)nullptr, 0);
  combine_smooth<<<dim3((NC * GG) / 1024), b256, 0, stream>>>(Po, Lsum, outS, outF);
  transpose_cast8<<<dim3(16, 256), b256, 0, stream>>>(outS, smoT8, 512, NC);
  // ---- fused heads: Ucat[:, h*512:] = sigmoid(Ah_h enc^T) @ smoothed ----
  attn_f8<<<dim3(1, 128, 4), b256, 0, stream>>>(Ahb, encb, smoT8, Ucat, 2048);
  // ---- final += (Ucat @ GTcat^T) / N   (single K=2048 GEMM) ----
  gemm_bt<<<dim3(4, 128), b256, 0, stream>>>(Ucat, 2048, GTc, 2048, 2048,
                                             3, (const float*)nullptr,
                                             (const float*)nullptr, 0,
                                             outF, (short*)nullptr, 512, 1.0f / NC);
}